// Round 9
// baseline (593.041 us; speedup 1.0000x reference)
//
#include <hip/hip_runtime.h>
#include <hip/hip_bf16.h>
#include <stdint.h>

// MoE top-2 (T=8192, D=1024, H=2816, E=8) — sparse grouped-GEMM implementation.
// R8 (resubmit after infra failure): gemm2 epilogue atomic-combine into out
// (combine kernel + Y buffer gone; out zeroed via memsetAsync; pos->token/-1
// pad guard); router fused into the transpose launch; 128-row segment padding.
// gemm1 byte-identical to R7.

#define T_TOK 8192
#define D_DIM 1024
#define H_DIM 2816
#define E_EXP 8
#define NSLOT 16384       // T * 2
#define CAP_ROWS 18432
#define MT_MAX 136        // 128-row tiles

// meta int layout
#define MI_T2 1
#define MI_POS 8
#define MI_MTE2 16
#define MI_MTB2 (16 + MT_MAX)

typedef __attribute__((ext_vector_type(8))) short short8;
typedef __attribute__((ext_vector_type(4))) float f32x4;

#define GLD16(gsrc, ldst) __builtin_amdgcn_global_load_lds( \
    (const __attribute__((address_space(1))) void*)(gsrc),  \
    (__attribute__((address_space(3))) void*)(ldst), 16, 0, 0)

// ---------------- merged: weight transposes + router ----------------
// blocks [0, 11264): w13 interleaved transpose, (E,D,H)x2 -> (E,2H,D)
// blocks [11264, 16896): w2 transpose, (E,H,D) -> (E,D,H)
// blocks [16896, 18944): router (4 tokens/block)
__global__ __launch_bounds__(256) void transpose_router(const float* __restrict__ w1,
                                                        const float* __restrict__ w3,
                                                        const float* __restrict__ w2,
                                                        __hip_bfloat16* __restrict__ w13t,
                                                        __hip_bfloat16* __restrict__ w2t,
                                                        const float* __restrict__ x,
                                                        const float* __restrict__ Wr,
                                                        float* __restrict__ Pbuf,
                                                        int* __restrict__ expert_sel,
                                                        float* __restrict__ slot_w) {
  __shared__ float tile[64][65];
  __shared__ float sP[4][8];
  int bid = blockIdx.x, tid = threadIdx.x;
  int lc = (tid & 15) * 4;
  int lr = tid >> 4;
  if (bid < 11264) {
    int z = bid / 704, rem = bid % 704;
    int bx = rem % 44, by = rem / 44;
    int e = z >> 1, w3f = z & 1;
    const float* in = w3f ? w3 : w1;
    int h0 = bx * 64, d0 = by * 64;
    const float* src = in + ((size_t)e * D_DIM + d0) * H_DIM + h0;
#pragma unroll
    for (int i = 0; i < 4; i++) {
      float4 v = *(const float4*)(src + (size_t)(lr + i * 16) * H_DIM + lc);
      tile[lr + i * 16][lc + 0] = v.x;
      tile[lr + i * 16][lc + 1] = v.y;
      tile[lr + i * 16][lc + 2] = v.z;
      tile[lr + i * 16][lc + 3] = v.w;
    }
    __syncthreads();
    __hip_bfloat16* dstE = w13t + (size_t)e * (2 * H_DIM) * D_DIM;
    int rB = (tid & 7) * 8;  // d offset within tile
#pragma unroll
    for (int i = 0; i < 2; i++) {
      int hh = (tid >> 3) + i * 32;
      int habs = h0 + hh;
      int rw = 2 * (habs & ~15) + (habs & 15) + (w3f ? 16 : 0);
      __align__(16) __hip_bfloat16 o[8];
#pragma unroll
      for (int k = 0; k < 8; k++) o[k] = __float2bfloat16(tile[rB + k][hh]);
      *(short8*)(dstE + (size_t)rw * D_DIM + d0 + rB) = *(const short8*)o;
    }
  } else if (bid < 16896) {
    int b2 = bid - 11264;
    int e = b2 / 704, rem = b2 % 704;
    int bx = rem % 16, by = rem / 16;
    int c0 = bx * 64, r0 = by * 64;
    const float* src = w2 + ((size_t)e * H_DIM + r0) * D_DIM + c0;
#pragma unroll
    for (int i = 0; i < 4; i++) {
      float4 v = *(const float4*)(src + (size_t)(lr + i * 16) * D_DIM + lc);
      tile[lr + i * 16][lc + 0] = v.x;
      tile[lr + i * 16][lc + 1] = v.y;
      tile[lr + i * 16][lc + 2] = v.z;
      tile[lr + i * 16][lc + 3] = v.w;
    }
    __syncthreads();
    __hip_bfloat16* dst = w2t + ((size_t)e * D_DIM + c0) * H_DIM + r0;
    int rB = (tid & 7) * 8;
#pragma unroll
    for (int i = 0; i < 2; i++) {
      int c = (tid >> 3) + i * 32;
      __align__(16) __hip_bfloat16 o[8];
#pragma unroll
      for (int k = 0; k < 8; k++) o[k] = __float2bfloat16(tile[rB + k][c]);
      *(short8*)(dst + (size_t)c * H_DIM + rB) = *(const short8*)o;
    }
  } else {
    int rb = bid - 16896;
    int wave = tid >> 6, lane = tid & 63;
    int tok = rb * 4 + wave;
    const float* xr = x + (size_t)tok * D_DIM;
    float acc[8];
#pragma unroll
    for (int e = 0; e < 8; e++) acc[e] = 0.f;
    for (int d = lane; d < D_DIM; d += 64) {
      float xv = xr[d];
      const float4* w4 = (const float4*)(Wr + d * 8);
      float4 wa = w4[0], wb = w4[1];
      acc[0] += xv * wa.x; acc[1] += xv * wa.y; acc[2] += xv * wa.z; acc[3] += xv * wa.w;
      acc[4] += xv * wb.x; acc[5] += xv * wb.y; acc[6] += xv * wb.z; acc[7] += xv * wb.w;
    }
#pragma unroll
    for (int e = 0; e < 8; e++) {
#pragma unroll
      for (int off = 32; off >= 1; off >>= 1) acc[e] += __shfl_xor(acc[e], off);
    }
    float mx = acc[0];
#pragma unroll
    for (int e = 1; e < 8; e++) mx = fmaxf(mx, acc[e]);
    float p[8], s = 0.f;
#pragma unroll
    for (int e = 0; e < 8; e++) { p[e] = expf(acc[e] - mx); s += p[e]; }
    float inv = 1.f / s;
#pragma unroll
    for (int e = 0; e < 8; e++) p[e] *= inv;
    int i0 = 0;
#pragma unroll
    for (int e = 1; e < 8; e++) if (p[e] > p[i0]) i0 = e;
    int i1 = (i0 == 0) ? 1 : 0;
#pragma unroll
    for (int e = 0; e < 8; e++) if (e != i0 && p[e] > p[i1]) i1 = e;
    float wsum = p[i0] + p[i1];
    if (lane == 0) {
      expert_sel[tok * 2] = i0;
      expert_sel[tok * 2 + 1] = i1;
      slot_w[tok * 2] = p[i0] / wsum;
      slot_w[tok * 2 + 1] = p[i1] / wsum;
#pragma unroll
      for (int e = 0; e < 8; e++) sP[wave][e] = p[e];
    }
    __syncthreads();
    if (tid < 8)
      Pbuf[tid * 2048 + rb] = sP[0][tid] + sP[1][tid] + sP[2][tid] + sP[3][tid];
  }
}

// ---------------- offsets: histogram + tile list + aux loss ----------------
__global__ __launch_bounds__(256) void offsets_kernel(const int* __restrict__ expert_sel,
                                                      int* __restrict__ meta,
                                                      const float* __restrict__ Pbuf,
                                                      float* __restrict__ aux_out) {
  int t = threadIdx.x;
  unsigned long long pA = 0, pB = 0;
  for (int i = 0; i < 64; i++) {
    int e = expert_sel[i * 256 + t];
    if (e < 4) pA += 1ull << (e * 16);
    else       pB += 1ull << ((e - 4) * 16);
  }
#pragma unroll
  for (int off = 32; off >= 1; off >>= 1) {
    pA += __shfl_xor(pA, off);
    pB += __shfl_xor(pB, off);
  }
  __shared__ unsigned long long sA[4], sB[4];
  __shared__ float red[8][33];
  int wave = t >> 6, lane = t & 63;
  if (lane == 0) { sA[wave] = pA; sB[wave] = pB; }
  int ee = t >> 5, j = t & 31;
  float s = 0.f;
  for (int c = j; c < 2048; c += 32) s += Pbuf[ee * 2048 + c];
  red[ee][j] = s;
  __syncthreads();
  if (t == 0) {
    unsigned long long A = sA[0] + sA[1] + sA[2] + sA[3];
    unsigned long long B = sB[0] + sB[1] + sB[2] + sB[3];
    int cnt[8];
    for (int e = 0; e < 4; e++) cnt[e] = (int)((A >> (e * 16)) & 0xFFFF);
    for (int e = 0; e < 4; e++) cnt[4 + e] = (int)((B >> (e * 16)) & 0xFFFF);
    float psum[8];
    for (int e = 0; e < 8; e++) {
      float ss = 0.f;
      for (int k = 0; k < 32; k++) ss += red[e][k];
      psum[e] = ss;
    }
    int off = 0, n2 = 0;
    float aux = 0.f;
    for (int e = 0; e < 8; e++) {
      int c = cnt[e];
      meta[MI_POS + e] = off;
      int t2 = (c + 127) >> 7;
      for (int jj = 0; jj < t2; jj++) { meta[MI_MTE2 + n2] = e; meta[MI_MTB2 + n2] = off + jj * 128; n2++; }
      off += t2 * 128;
      aux += ((float)c / 16384.f) * (psum[e] / 8192.f);
    }
    meta[MI_T2] = n2;
    *aux_out = 8.f * aux;
  }
}

// ---------------- assign: ballot-aggregated positions + pos->tok/weight ----------------
__global__ __launch_bounds__(256) void assign_kernel(const int* __restrict__ expert_sel,
                                                     const float* __restrict__ slot_w,
                                                     int* __restrict__ meta,
                                                     int* __restrict__ slot_pos,
                                                     int* __restrict__ tok_of_pos,
                                                     float* __restrict__ w_of_pos) {
  int tid = threadIdx.x, wave = tid >> 6, lane = tid & 63;
  int slot = blockIdx.x * 256 + tid;
  int e = expert_sel[slot];
  __shared__ int cnt[4][8];
  __shared__ int base[8];
  __shared__ int woff[4][8];
  int rank = 0;
#pragma unroll
  for (int ee = 0; ee < 8; ee++) {
    unsigned long long msk = __ballot(e == ee);
    if (lane == 0) cnt[wave][ee] = __popcll(msk);
    if (e == ee) rank = __popcll(msk & ((1ull << lane) - 1ull));
  }
  __syncthreads();
  if (tid < 8) {
    int c0 = cnt[0][tid], c1 = cnt[1][tid], c2 = cnt[2][tid], c3 = cnt[3][tid];
    int tot = c0 + c1 + c2 + c3;
    base[tid] = atomicAdd(&meta[MI_POS + tid], tot);
    woff[0][tid] = 0; woff[1][tid] = c0; woff[2][tid] = c0 + c1; woff[3][tid] = c0 + c1 + c2;
  }
  __syncthreads();
  int pos = base[e] + woff[wave][e] + rank;
  slot_pos[slot] = pos;
  tok_of_pos[pos] = slot >> 1;
  w_of_pos[pos] = slot_w[slot];
}

// ---------------- gather: one read per token, write both slots ----------------
__global__ __launch_bounds__(256) void gather_kernel(const int* __restrict__ slot_pos,
                                                     const float* __restrict__ x,
                                                     __hip_bfloat16* __restrict__ Xg) {
  int wave = threadIdx.x >> 6, lane = threadIdx.x & 63;
  int tok = blockIdx.x * 4 + wave;
  int p0 = slot_pos[tok * 2], p1 = slot_pos[tok * 2 + 1];
  const float4* src = (const float4*)(x + (size_t)tok * D_DIM);
  __hip_bfloat16* d0 = Xg + (size_t)p0 * D_DIM;
  __hip_bfloat16* d1 = Xg + (size_t)p1 * D_DIM;
#pragma unroll
  for (int p = 0; p < 4; p++) {
    float4 v = src[p * 64 + lane];
    union { ushort4 u4; __hip_bfloat16 h[4]; } cv;
    cv.h[0] = __float2bfloat16(v.x);
    cv.h[1] = __float2bfloat16(v.y);
    cv.h[2] = __float2bfloat16(v.z);
    cv.h[3] = __float2bfloat16(v.w);
    *(ushort4*)(d0 + (p * 64 + lane) * 4) = cv.u4;
    *(ushort4*)(d1 + (p * 64 + lane) * 4) = cv.u4;
  }
}

// ---------------- GEMM helpers (BK=64) ----------------
__device__ __forceinline__ short8 frag_read64(const char* tile, int row, int gk) {
  int byte = (row << 7) | ((gk ^ (row & 7)) << 4);
  return *(const short8*)(tile + byte);
}

template <int NITER, int BLK>
__device__ __forceinline__ void stage_rowsT(const __hip_bfloat16* gbase, int ld, char* tile,
                                            int tid) {
#pragma unroll
  for (int i = 0; i < NITER; i++) {
    int L = i * (BLK * 16) + tid * 16;
    int row = L >> 7;
    int g = (L >> 4) & 7;
    int gs = g ^ (row & 7);  // pre-swizzled global source, linear LDS dest
    const char* src = (const char*)(gbase + (size_t)row * ld) + gs * 16;
    GLD16(src, tile + i * (BLK * 16) + (tid >> 6) * 1024);
  }
}

__device__ __forceinline__ void tile_from_bid(int bid, int nwg, int mmax, int* m, int* n) {
  int cpx = nwg >> 3;
  int u = (bid & 7) * cpx + (bid >> 3);
  *n = u / mmax;
  *m = u % mmax;
}

// ---------------- GEMM1: Hb = silu/fuse( Xg @ w13t^T ), 128x(256 interleaved) ----------------
__global__ __launch_bounds__(256, 2) void gemm1_kernel(const __hip_bfloat16* __restrict__ Xg,
                                                       const __hip_bfloat16* __restrict__ w13t,
                                                       __hip_bfloat16* __restrict__ Hb,
                                                       const int* __restrict__ meta) {
  int m, nIdx;
  tile_from_bid(blockIdx.x, (2 * H_DIM / 256) * MT_MAX, MT_MAX, &m, &nIdx);
  if (m >= meta[MI_T2]) return;
  int e = meta[MI_MTE2 + m];
  int row0 = meta[MI_MTB2 + m];
  int n0 = nIdx * 256;
  __shared__ __align__(16) char ldsA[16384];
  __shared__ __align__(16) char ldsB[32768];
  int tid = threadIdx.x, wave = tid >> 6, lane = tid & 63;
  int wr = wave >> 1, wc = wave & 1;
  const __hip_bfloat16* Ab = Xg + (size_t)row0 * D_DIM;
  const __hip_bfloat16* Bb = w13t + ((size_t)e * (2 * H_DIM) + n0) * D_DIM;

  f32x4 acc[4][8];
#pragma unroll
  for (int i = 0; i < 4; i++)
#pragma unroll
    for (int j = 0; j < 8; j++) acc[i][j] = 0.f;

  int rsel = lane & 15, kg = lane >> 4;
  for (int k0 = 0; k0 < D_DIM; k0 += 64) {
    stage_rowsT<4, 256>(Ab + k0, D_DIM, ldsA, tid);
    stage_rowsT<8, 256>(Bb + k0, D_DIM, ldsB, tid);
    asm volatile("s_waitcnt vmcnt(0)" ::: "memory");
    __syncthreads();
#pragma unroll
    for (int kk = 0; kk < 2; kk++) {
      int gk = kk * 4 + kg;
      short8 a[4], b[8];
#pragma unroll
      for (int f = 0; f < 4; f++) a[f] = frag_read64(ldsA, wr * 64 + f * 16 + rsel, gk);
#pragma unroll
      for (int f = 0; f < 8; f++) b[f] = frag_read64(ldsB, wc * 128 + f * 16 + rsel, gk);
#pragma unroll
      for (int fm = 0; fm < 4; fm++)
#pragma unroll
        for (int fn = 0; fn < 8; fn++)
          acc[fm][fn] = __builtin_amdgcn_mfma_f32_16x16x32_bf16(a[fm], b[fn], acc[fm][fn], 0, 0, 0);
    }
    __syncthreads();
  }
  int rq = lane >> 4;
#pragma unroll
  for (int fm = 0; fm < 4; fm++)
#pragma unroll
    for (int fnp = 0; fnp < 4; fnp++)
#pragma unroll
      for (int j = 0; j < 4; j++) {
        float v1 = acc[fm][2 * fnp][j], v3 = acc[fm][2 * fnp + 1][j];
        float h = (v1 / (1.f + expf(-v1))) * v3;  // silu(v1)*v3
        int r = row0 + wr * 64 + fm * 16 + rq * 4 + j;
        int c = (n0 >> 1) + wc * 64 + fnp * 16 + rsel;
        Hb[(size_t)r * H_DIM + c] = __float2bfloat16(h);
      }
}

// ---------------- GEMM2: out[tok] += w * (Hb @ w2t^T), atomic epilogue ----------------
__global__ __launch_bounds__(256, 2) void gemm2_kernel(const __hip_bfloat16* __restrict__ Hb,
                                                       const __hip_bfloat16* __restrict__ w2t,
                                                       const int* __restrict__ tok_of_pos,
                                                       const float* __restrict__ w_of_pos,
                                                       float* __restrict__ outp,
                                                       const int* __restrict__ meta) {
  int m, nIdx;
  tile_from_bid(blockIdx.x, (D_DIM / 256) * MT_MAX, MT_MAX, &m, &nIdx);
  if (m >= meta[MI_T2]) return;
  int e = meta[MI_MTE2 + m];
  int row0 = meta[MI_MTB2 + m];
  int n0 = nIdx * 256;
  __shared__ __align__(16) char ldsA[16384];
  __shared__ __align__(16) char ldsB[32768];
  int tid = threadIdx.x, wave = tid >> 6, lane = tid & 63;
  int wr = wave >> 1, wc = wave & 1;
  const __hip_bfloat16* Ab = Hb + (size_t)row0 * H_DIM;
  const __hip_bfloat16* Bb = w2t + ((size_t)e * D_DIM + n0) * H_DIM;

  f32x4 acc[4][8];
#pragma unroll
  for (int i = 0; i < 4; i++)
#pragma unroll
    for (int j = 0; j < 8; j++) acc[i][j] = 0.f;

  int rsel = lane & 15, kg = lane >> 4;
  for (int k0 = 0; k0 < H_DIM; k0 += 64) {
    stage_rowsT<4, 256>(Ab + k0, H_DIM, ldsA, tid);
    stage_rowsT<8, 256>(Bb + k0, H_DIM, ldsB, tid);
    asm volatile("s_waitcnt vmcnt(0)" ::: "memory");
    __syncthreads();
#pragma unroll
    for (int kk = 0; kk < 2; kk++) {
      int gk = kk * 4 + kg;
      short8 a[4], b[8];
#pragma unroll
      for (int f = 0; f < 4; f++) a[f] = frag_read64(ldsA, wr * 64 + f * 16 + rsel, gk);
#pragma unroll
      for (int f = 0; f < 8; f++) b[f] = frag_read64(ldsB, wc * 128 + f * 16 + rsel, gk);
#pragma unroll
      for (int fm = 0; fm < 4; fm++)
#pragma unroll
        for (int fn = 0; fn < 8; fn++)
          acc[fm][fn] = __builtin_amdgcn_mfma_f32_16x16x32_bf16(a[fm], b[fn], acc[fm][fn], 0, 0, 0);
    }
    __syncthreads();
  }
  int rq = lane >> 4;
#pragma unroll
  for (int fm = 0; fm < 4; fm++)
#pragma unroll
    for (int j = 0; j < 4; j++) {
      int r = row0 + wr * 64 + fm * 16 + rq * 4 + j;
      int tok = tok_of_pos[r];
      if (tok < 0) continue;  // padding row
      float w = w_of_pos[r];
      float* orow = outp + (size_t)tok * D_DIM;
#pragma unroll
      for (int fn = 0; fn < 8; fn++) {
        int c = n0 + wc * 128 + fn * 16 + rsel;
        atomicAdd(&orow[c], w * acc[fm][fn][j]);
      }
    }
}

// ---------------- launch ----------------
extern "C" void kernel_launch(void* const* d_in, const int* in_sizes, int n_in,
                              void* d_out, int out_size, void* d_ws, size_t ws_size,
                              hipStream_t stream) {
  const float* x = (const float*)d_in[0];
  const float* Wr = (const float*)d_in[1];
  const float* w1 = (const float*)d_in[2];
  const float* w3 = (const float*)d_in[3];
  const float* w2 = (const float*)d_in[4];
  float* outp = (float*)d_out;

  char* ws = (char*)d_ws;
  size_t off = 0;
  auto alloc = [&](size_t bytes) -> char* {
    char* p = ws + off;
    off += (bytes + 255) & ~(size_t)255;
    return p;
  };
  __hip_bfloat16* w13t = (__hip_bfloat16*)alloc((size_t)E_EXP * 2 * H_DIM * D_DIM * 2);
  __hip_bfloat16* w2t = (__hip_bfloat16*)alloc((size_t)E_EXP * D_DIM * H_DIM * 2);
  __hip_bfloat16* Xg = (__hip_bfloat16*)alloc((size_t)CAP_ROWS * D_DIM * 2);
  __hip_bfloat16* Hb = (__hip_bfloat16*)alloc((size_t)CAP_ROWS * H_DIM * 2);
  float* slot_w = (float*)alloc(NSLOT * 4);
  int* slot_pos = (int*)alloc(NSLOT * 4);
  int* expert_sel = (int*)alloc(NSLOT * 4);
  int* tok_of_pos = (int*)alloc(CAP_ROWS * 4);
  float* w_of_pos = (float*)alloc(CAP_ROWS * 4);
  float* Pbuf = (float*)alloc(2048 * 8 * 4);
  int* meta = (int*)alloc(2048);
  (void)ws_size; (void)in_sizes; (void)n_in;

  hipMemsetAsync(outp, 0, (size_t)out_size * 4, stream);
  hipMemsetAsync(tok_of_pos, 0xFF, (size_t)CAP_ROWS * 4, stream);

  transpose_router<<<dim3(18944), dim3(256), 0, stream>>>(w1, w3, w2, w13t, w2t,
                                                          x, Wr, Pbuf, expert_sel, slot_w);
  offsets_kernel<<<dim3(1), dim3(256), 0, stream>>>(expert_sel, meta, Pbuf, outp + (size_t)T_TOK * D_DIM);
  assign_kernel<<<dim3(NSLOT / 256), dim3(256), 0, stream>>>(expert_sel, slot_w, meta, slot_pos,
                                                             tok_of_pos, w_of_pos);
  gather_kernel<<<dim3(T_TOK / 4), dim3(256), 0, stream>>>(slot_pos, x, Xg);
  gemm1_kernel<<<dim3((2 * H_DIM / 256) * MT_MAX), dim3(256), 0, stream>>>(Xg, w13t, Hb, meta);
  gemm2_kernel<<<dim3((D_DIM / 256) * MT_MAX), dim3(256), 0, stream>>>(Hb, w2t, tok_of_pos,
                                                                       w_of_pos, outp, meta);
}

// Round 10
// 550.192 us; speedup vs baseline: 1.0779x; 1.0779x over previous
//
#include <hip/hip_runtime.h>
#include <hip/hip_bf16.h>
#include <stdint.h>

// MoE top-2 (T=8192, D=1024, H=2816, E=8) — sparse grouped-GEMM implementation.
// R10: revert atomic epilogue (measured −58us loser) -> bf16 Y + combine (R7
// measured-good); keep fused transpose+router launch (R9); no memsets, no
// pos->tok maps. 7 dispatches total.

#define T_TOK 8192
#define D_DIM 1024
#define H_DIM 2816
#define E_EXP 8
#define NSLOT 16384       // T * 2
#define CAP_ROWS 18432
#define MT_MAX 136        // 128-row tiles

// meta int layout
#define MI_T2 1
#define MI_POS 8
#define MI_MTE2 16
#define MI_MTB2 (16 + MT_MAX)

typedef __attribute__((ext_vector_type(8))) short short8;
typedef __attribute__((ext_vector_type(4))) float f32x4;

#define GLD16(gsrc, ldst) __builtin_amdgcn_global_load_lds( \
    (const __attribute__((address_space(1))) void*)(gsrc),  \
    (__attribute__((address_space(3))) void*)(ldst), 16, 0, 0)

// ---------------- merged: weight transposes + router ----------------
// blocks [0, 11264): w13 interleaved transpose, (E,D,H)x2 -> (E,2H,D)
// blocks [11264, 16896): w2 transpose, (E,H,D) -> (E,D,H)
// blocks [16896, 18944): router (4 tokens/block)
__global__ __launch_bounds__(256) void transpose_router(const float* __restrict__ w1,
                                                        const float* __restrict__ w3,
                                                        const float* __restrict__ w2,
                                                        __hip_bfloat16* __restrict__ w13t,
                                                        __hip_bfloat16* __restrict__ w2t,
                                                        const float* __restrict__ x,
                                                        const float* __restrict__ Wr,
                                                        float* __restrict__ Pbuf,
                                                        int* __restrict__ expert_sel,
                                                        float* __restrict__ slot_w) {
  __shared__ float tile[64][65];
  __shared__ float sP[4][8];
  int bid = blockIdx.x, tid = threadIdx.x;
  int lc = (tid & 15) * 4;
  int lr = tid >> 4;
  if (bid < 11264) {
    int z = bid / 704, rem = bid % 704;
    int bx = rem % 44, by = rem / 44;
    int e = z >> 1, w3f = z & 1;
    const float* in = w3f ? w3 : w1;
    int h0 = bx * 64, d0 = by * 64;
    const float* src = in + ((size_t)e * D_DIM + d0) * H_DIM + h0;
#pragma unroll
    for (int i = 0; i < 4; i++) {
      float4 v = *(const float4*)(src + (size_t)(lr + i * 16) * H_DIM + lc);
      tile[lr + i * 16][lc + 0] = v.x;
      tile[lr + i * 16][lc + 1] = v.y;
      tile[lr + i * 16][lc + 2] = v.z;
      tile[lr + i * 16][lc + 3] = v.w;
    }
    __syncthreads();
    __hip_bfloat16* dstE = w13t + (size_t)e * (2 * H_DIM) * D_DIM;
    int rB = (tid & 7) * 8;  // d offset within tile
#pragma unroll
    for (int i = 0; i < 2; i++) {
      int hh = (tid >> 3) + i * 32;
      int habs = h0 + hh;
      int rw = 2 * (habs & ~15) + (habs & 15) + (w3f ? 16 : 0);
      __align__(16) __hip_bfloat16 o[8];
#pragma unroll
      for (int k = 0; k < 8; k++) o[k] = __float2bfloat16(tile[rB + k][hh]);
      *(short8*)(dstE + (size_t)rw * D_DIM + d0 + rB) = *(const short8*)o;
    }
  } else if (bid < 16896) {
    int b2 = bid - 11264;
    int e = b2 / 704, rem = b2 % 704;
    int bx = rem % 16, by = rem / 16;
    int c0 = bx * 64, r0 = by * 64;
    const float* src = w2 + ((size_t)e * H_DIM + r0) * D_DIM + c0;
#pragma unroll
    for (int i = 0; i < 4; i++) {
      float4 v = *(const float4*)(src + (size_t)(lr + i * 16) * D_DIM + lc);
      tile[lr + i * 16][lc + 0] = v.x;
      tile[lr + i * 16][lc + 1] = v.y;
      tile[lr + i * 16][lc + 2] = v.z;
      tile[lr + i * 16][lc + 3] = v.w;
    }
    __syncthreads();
    __hip_bfloat16* dst = w2t + ((size_t)e * D_DIM + c0) * H_DIM + r0;
    int rB = (tid & 7) * 8;
#pragma unroll
    for (int i = 0; i < 2; i++) {
      int c = (tid >> 3) + i * 32;
      __align__(16) __hip_bfloat16 o[8];
#pragma unroll
      for (int k = 0; k < 8; k++) o[k] = __float2bfloat16(tile[rB + k][c]);
      *(short8*)(dst + (size_t)c * H_DIM + rB) = *(const short8*)o;
    }
  } else {
    int rb = bid - 16896;
    int wave = tid >> 6, lane = tid & 63;
    int tok = rb * 4 + wave;
    const float* xr = x + (size_t)tok * D_DIM;
    float acc[8];
#pragma unroll
    for (int e = 0; e < 8; e++) acc[e] = 0.f;
    for (int d = lane; d < D_DIM; d += 64) {
      float xv = xr[d];
      const float4* w4 = (const float4*)(Wr + d * 8);
      float4 wa = w4[0], wb = w4[1];
      acc[0] += xv * wa.x; acc[1] += xv * wa.y; acc[2] += xv * wa.z; acc[3] += xv * wa.w;
      acc[4] += xv * wb.x; acc[5] += xv * wb.y; acc[6] += xv * wb.z; acc[7] += xv * wb.w;
    }
#pragma unroll
    for (int e = 0; e < 8; e++) {
#pragma unroll
      for (int off = 32; off >= 1; off >>= 1) acc[e] += __shfl_xor(acc[e], off);
    }
    float mx = acc[0];
#pragma unroll
    for (int e = 1; e < 8; e++) mx = fmaxf(mx, acc[e]);
    float p[8], s = 0.f;
#pragma unroll
    for (int e = 0; e < 8; e++) { p[e] = expf(acc[e] - mx); s += p[e]; }
    float inv = 1.f / s;
#pragma unroll
    for (int e = 0; e < 8; e++) p[e] *= inv;
    int i0 = 0;
#pragma unroll
    for (int e = 1; e < 8; e++) if (p[e] > p[i0]) i0 = e;
    int i1 = (i0 == 0) ? 1 : 0;
#pragma unroll
    for (int e = 0; e < 8; e++) if (e != i0 && p[e] > p[i1]) i1 = e;
    float wsum = p[i0] + p[i1];
    if (lane == 0) {
      expert_sel[tok * 2] = i0;
      expert_sel[tok * 2 + 1] = i1;
      slot_w[tok * 2] = p[i0] / wsum;
      slot_w[tok * 2 + 1] = p[i1] / wsum;
#pragma unroll
      for (int e = 0; e < 8; e++) sP[wave][e] = p[e];
    }
    __syncthreads();
    if (tid < 8)
      Pbuf[tid * 2048 + rb] = sP[0][tid] + sP[1][tid] + sP[2][tid] + sP[3][tid];
  }
}

// ---------------- offsets: histogram + tile list + aux loss ----------------
__global__ __launch_bounds__(256) void offsets_kernel(const int* __restrict__ expert_sel,
                                                      int* __restrict__ meta,
                                                      const float* __restrict__ Pbuf,
                                                      float* __restrict__ aux_out) {
  int t = threadIdx.x;
  unsigned long long pA = 0, pB = 0;
  for (int i = 0; i < 64; i++) {
    int e = expert_sel[i * 256 + t];
    if (e < 4) pA += 1ull << (e * 16);
    else       pB += 1ull << ((e - 4) * 16);
  }
#pragma unroll
  for (int off = 32; off >= 1; off >>= 1) {
    pA += __shfl_xor(pA, off);
    pB += __shfl_xor(pB, off);
  }
  __shared__ unsigned long long sA[4], sB[4];
  __shared__ float red[8][33];
  int wave = t >> 6, lane = t & 63;
  if (lane == 0) { sA[wave] = pA; sB[wave] = pB; }
  int ee = t >> 5, j = t & 31;
  float s = 0.f;
  for (int c = j; c < 2048; c += 32) s += Pbuf[ee * 2048 + c];
  red[ee][j] = s;
  __syncthreads();
  if (t == 0) {
    unsigned long long A = sA[0] + sA[1] + sA[2] + sA[3];
    unsigned long long B = sB[0] + sB[1] + sB[2] + sB[3];
    int cnt[8];
    for (int e = 0; e < 4; e++) cnt[e] = (int)((A >> (e * 16)) & 0xFFFF);
    for (int e = 0; e < 4; e++) cnt[4 + e] = (int)((B >> (e * 16)) & 0xFFFF);
    float psum[8];
    for (int e = 0; e < 8; e++) {
      float ss = 0.f;
      for (int k = 0; k < 32; k++) ss += red[e][k];
      psum[e] = ss;
    }
    int off = 0, n2 = 0;
    float aux = 0.f;
    for (int e = 0; e < 8; e++) {
      int c = cnt[e];
      meta[MI_POS + e] = off;
      int t2 = (c + 127) >> 7;
      for (int jj = 0; jj < t2; jj++) { meta[MI_MTE2 + n2] = e; meta[MI_MTB2 + n2] = off + jj * 128; n2++; }
      off += t2 * 128;
      aux += ((float)c / 16384.f) * (psum[e] / 8192.f);
    }
    meta[MI_T2] = n2;
    *aux_out = 8.f * aux;
  }
}

// ---------------- assign: ballot-aggregated positions ----------------
__global__ __launch_bounds__(256) void assign_kernel(const int* __restrict__ expert_sel,
                                                     int* __restrict__ meta,
                                                     int* __restrict__ slot_pos) {
  int tid = threadIdx.x, wave = tid >> 6, lane = tid & 63;
  int slot = blockIdx.x * 256 + tid;
  int e = expert_sel[slot];
  __shared__ int cnt[4][8];
  __shared__ int base[8];
  __shared__ int woff[4][8];
  int rank = 0;
#pragma unroll
  for (int ee = 0; ee < 8; ee++) {
    unsigned long long msk = __ballot(e == ee);
    if (lane == 0) cnt[wave][ee] = __popcll(msk);
    if (e == ee) rank = __popcll(msk & ((1ull << lane) - 1ull));
  }
  __syncthreads();
  if (tid < 8) {
    int c0 = cnt[0][tid], c1 = cnt[1][tid], c2 = cnt[2][tid], c3 = cnt[3][tid];
    int tot = c0 + c1 + c2 + c3;
    base[tid] = atomicAdd(&meta[MI_POS + tid], tot);
    woff[0][tid] = 0; woff[1][tid] = c0; woff[2][tid] = c0 + c1; woff[3][tid] = c0 + c1 + c2;
  }
  __syncthreads();
  slot_pos[slot] = base[e] + woff[wave][e] + rank;
}

// ---------------- gather: one read per token, write both slots ----------------
__global__ __launch_bounds__(256) void gather_kernel(const int* __restrict__ slot_pos,
                                                     const float* __restrict__ x,
                                                     __hip_bfloat16* __restrict__ Xg) {
  int wave = threadIdx.x >> 6, lane = threadIdx.x & 63;
  int tok = blockIdx.x * 4 + wave;
  int p0 = slot_pos[tok * 2], p1 = slot_pos[tok * 2 + 1];
  const float4* src = (const float4*)(x + (size_t)tok * D_DIM);
  __hip_bfloat16* d0 = Xg + (size_t)p0 * D_DIM;
  __hip_bfloat16* d1 = Xg + (size_t)p1 * D_DIM;
#pragma unroll
  for (int p = 0; p < 4; p++) {
    float4 v = src[p * 64 + lane];
    union { ushort4 u4; __hip_bfloat16 h[4]; } cv;
    cv.h[0] = __float2bfloat16(v.x);
    cv.h[1] = __float2bfloat16(v.y);
    cv.h[2] = __float2bfloat16(v.z);
    cv.h[3] = __float2bfloat16(v.w);
    *(ushort4*)(d0 + (p * 64 + lane) * 4) = cv.u4;
    *(ushort4*)(d1 + (p * 64 + lane) * 4) = cv.u4;
  }
}

// ---------------- GEMM helpers (BK=64) ----------------
__device__ __forceinline__ short8 frag_read64(const char* tile, int row, int gk) {
  int byte = (row << 7) | ((gk ^ (row & 7)) << 4);
  return *(const short8*)(tile + byte);
}

template <int NITER, int BLK>
__device__ __forceinline__ void stage_rowsT(const __hip_bfloat16* gbase, int ld, char* tile,
                                            int tid) {
#pragma unroll
  for (int i = 0; i < NITER; i++) {
    int L = i * (BLK * 16) + tid * 16;
    int row = L >> 7;
    int g = (L >> 4) & 7;
    int gs = g ^ (row & 7);  // pre-swizzled global source, linear LDS dest
    const char* src = (const char*)(gbase + (size_t)row * ld) + gs * 16;
    GLD16(src, tile + i * (BLK * 16) + (tid >> 6) * 1024);
  }
}

__device__ __forceinline__ void tile_from_bid(int bid, int nwg, int mmax, int* m, int* n) {
  int cpx = nwg >> 3;
  int u = (bid & 7) * cpx + (bid >> 3);
  *n = u / mmax;
  *m = u % mmax;
}

// ---------------- GEMM1: Hb = silu/fuse( Xg @ w13t^T ), 128x(256 interleaved) ----------------
__global__ __launch_bounds__(256, 2) void gemm1_kernel(const __hip_bfloat16* __restrict__ Xg,
                                                       const __hip_bfloat16* __restrict__ w13t,
                                                       __hip_bfloat16* __restrict__ Hb,
                                                       const int* __restrict__ meta) {
  int m, nIdx;
  tile_from_bid(blockIdx.x, (2 * H_DIM / 256) * MT_MAX, MT_MAX, &m, &nIdx);
  if (m >= meta[MI_T2]) return;
  int e = meta[MI_MTE2 + m];
  int row0 = meta[MI_MTB2 + m];
  int n0 = nIdx * 256;
  __shared__ __align__(16) char ldsA[16384];
  __shared__ __align__(16) char ldsB[32768];
  int tid = threadIdx.x, wave = tid >> 6, lane = tid & 63;
  int wr = wave >> 1, wc = wave & 1;
  const __hip_bfloat16* Ab = Xg + (size_t)row0 * D_DIM;
  const __hip_bfloat16* Bb = w13t + ((size_t)e * (2 * H_DIM) + n0) * D_DIM;

  f32x4 acc[4][8];
#pragma unroll
  for (int i = 0; i < 4; i++)
#pragma unroll
    for (int j = 0; j < 8; j++) acc[i][j] = 0.f;

  int rsel = lane & 15, kg = lane >> 4;
  for (int k0 = 0; k0 < D_DIM; k0 += 64) {
    stage_rowsT<4, 256>(Ab + k0, D_DIM, ldsA, tid);
    stage_rowsT<8, 256>(Bb + k0, D_DIM, ldsB, tid);
    asm volatile("s_waitcnt vmcnt(0)" ::: "memory");
    __syncthreads();
#pragma unroll
    for (int kk = 0; kk < 2; kk++) {
      int gk = kk * 4 + kg;
      short8 a[4], b[8];
#pragma unroll
      for (int f = 0; f < 4; f++) a[f] = frag_read64(ldsA, wr * 64 + f * 16 + rsel, gk);
#pragma unroll
      for (int f = 0; f < 8; f++) b[f] = frag_read64(ldsB, wc * 128 + f * 16 + rsel, gk);
#pragma unroll
      for (int fm = 0; fm < 4; fm++)
#pragma unroll
        for (int fn = 0; fn < 8; fn++)
          acc[fm][fn] = __builtin_amdgcn_mfma_f32_16x16x32_bf16(a[fm], b[fn], acc[fm][fn], 0, 0, 0);
    }
    __syncthreads();
  }
  int rq = lane >> 4;
#pragma unroll
  for (int fm = 0; fm < 4; fm++)
#pragma unroll
    for (int fnp = 0; fnp < 4; fnp++)
#pragma unroll
      for (int j = 0; j < 4; j++) {
        float v1 = acc[fm][2 * fnp][j], v3 = acc[fm][2 * fnp + 1][j];
        float h = (v1 / (1.f + expf(-v1))) * v3;  // silu(v1)*v3
        int r = row0 + wr * 64 + fm * 16 + rq * 4 + j;
        int c = (n0 >> 1) + wc * 64 + fnp * 16 + rsel;
        Hb[(size_t)r * H_DIM + c] = __float2bfloat16(h);
      }
}

// ---------------- GEMM2: Y = Hb @ w2t^T (bf16 out), 128x256 tile ----------------
__global__ __launch_bounds__(256, 2) void gemm2_kernel(const __hip_bfloat16* __restrict__ Hb,
                                                       const __hip_bfloat16* __restrict__ w2t,
                                                       __hip_bfloat16* __restrict__ Y,
                                                       const int* __restrict__ meta) {
  int m, nIdx;
  tile_from_bid(blockIdx.x, (D_DIM / 256) * MT_MAX, MT_MAX, &m, &nIdx);
  if (m >= meta[MI_T2]) return;
  int e = meta[MI_MTE2 + m];
  int row0 = meta[MI_MTB2 + m];
  int n0 = nIdx * 256;
  __shared__ __align__(16) char ldsA[16384];
  __shared__ __align__(16) char ldsB[32768];
  int tid = threadIdx.x, wave = tid >> 6, lane = tid & 63;
  int wr = wave >> 1, wc = wave & 1;
  const __hip_bfloat16* Ab = Hb + (size_t)row0 * H_DIM;
  const __hip_bfloat16* Bb = w2t + ((size_t)e * D_DIM + n0) * H_DIM;

  f32x4 acc[4][8];
#pragma unroll
  for (int i = 0; i < 4; i++)
#pragma unroll
    for (int j = 0; j < 8; j++) acc[i][j] = 0.f;

  int rsel = lane & 15, kg = lane >> 4;
  for (int k0 = 0; k0 < H_DIM; k0 += 64) {
    stage_rowsT<4, 256>(Ab + k0, H_DIM, ldsA, tid);
    stage_rowsT<8, 256>(Bb + k0, H_DIM, ldsB, tid);
    asm volatile("s_waitcnt vmcnt(0)" ::: "memory");
    __syncthreads();
#pragma unroll
    for (int kk = 0; kk < 2; kk++) {
      int gk = kk * 4 + kg;
      short8 a[4], b[8];
#pragma unroll
      for (int f = 0; f < 4; f++) a[f] = frag_read64(ldsA, wr * 64 + f * 16 + rsel, gk);
#pragma unroll
      for (int f = 0; f < 8; f++) b[f] = frag_read64(ldsB, wc * 128 + f * 16 + rsel, gk);
#pragma unroll
      for (int fm = 0; fm < 4; fm++)
#pragma unroll
        for (int fn = 0; fn < 8; fn++)
          acc[fm][fn] = __builtin_amdgcn_mfma_f32_16x16x32_bf16(a[fm], b[fn], acc[fm][fn], 0, 0, 0);
    }
    __syncthreads();
  }
  int rq = lane >> 4;
#pragma unroll
  for (int fm = 0; fm < 4; fm++)
#pragma unroll
    for (int fn = 0; fn < 8; fn++)
#pragma unroll
      for (int j = 0; j < 4; j++) {
        int r = row0 + wr * 64 + fm * 16 + rq * 4 + j;
        int c = n0 + wc * 128 + fn * 16 + rsel;
        Y[(size_t)r * D_DIM + c] = __float2bfloat16(acc[fm][fn][j]);
      }
}

// ---------------- combine: out[t] = w0*Y[p0] + w1*Y[p1] (bf16 Y) ----------------
__global__ __launch_bounds__(256) void combine_kernel(const int* __restrict__ slot_pos,
                                                      const float* __restrict__ slot_w,
                                                      const __hip_bfloat16* __restrict__ Y,
                                                      float* __restrict__ outp) {
  int tok = blockIdx.x;
  int p0 = slot_pos[tok * 2], p1 = slot_pos[tok * 2 + 1];
  float w0 = slot_w[tok * 2], w1 = slot_w[tok * 2 + 1];
  int i4 = threadIdx.x;  // 256 threads x 4 elems
  ushort4 a = *(const ushort4*)(Y + (size_t)p0 * D_DIM + i4 * 4);
  ushort4 b = *(const ushort4*)(Y + (size_t)p1 * D_DIM + i4 * 4);
  union { ushort u; __hip_bfloat16 h; } c0, c1;
  float4 r;
  c0.u = a.x; c1.u = b.x; r.x = w0 * __bfloat162float(c0.h) + w1 * __bfloat162float(c1.h);
  c0.u = a.y; c1.u = b.y; r.y = w0 * __bfloat162float(c0.h) + w1 * __bfloat162float(c1.h);
  c0.u = a.z; c1.u = b.z; r.z = w0 * __bfloat162float(c0.h) + w1 * __bfloat162float(c1.h);
  c0.u = a.w; c1.u = b.w; r.w = w0 * __bfloat162float(c0.h) + w1 * __bfloat162float(c1.h);
  ((float4*)(outp + (size_t)tok * D_DIM))[i4] = r;
}

// ---------------- launch ----------------
extern "C" void kernel_launch(void* const* d_in, const int* in_sizes, int n_in,
                              void* d_out, int out_size, void* d_ws, size_t ws_size,
                              hipStream_t stream) {
  const float* x = (const float*)d_in[0];
  const float* Wr = (const float*)d_in[1];
  const float* w1 = (const float*)d_in[2];
  const float* w3 = (const float*)d_in[3];
  const float* w2 = (const float*)d_in[4];
  float* outp = (float*)d_out;

  char* ws = (char*)d_ws;
  size_t off = 0;
  auto alloc = [&](size_t bytes) -> char* {
    char* p = ws + off;
    off += (bytes + 255) & ~(size_t)255;
    return p;
  };
  __hip_bfloat16* w13t = (__hip_bfloat16*)alloc((size_t)E_EXP * 2 * H_DIM * D_DIM * 2);
  __hip_bfloat16* w2t = (__hip_bfloat16*)alloc((size_t)E_EXP * D_DIM * H_DIM * 2);
  __hip_bfloat16* Xg = (__hip_bfloat16*)alloc((size_t)CAP_ROWS * D_DIM * 2);
  __hip_bfloat16* Hb = (__hip_bfloat16*)alloc((size_t)CAP_ROWS * H_DIM * 2);
  __hip_bfloat16* Y = (__hip_bfloat16*)alloc((size_t)CAP_ROWS * D_DIM * 2);
  float* slot_w = (float*)alloc(NSLOT * 4);
  int* slot_pos = (int*)alloc(NSLOT * 4);
  int* expert_sel = (int*)alloc(NSLOT * 4);
  float* Pbuf = (float*)alloc(2048 * 8 * 4);
  int* meta = (int*)alloc(2048);
  (void)ws_size; (void)in_sizes; (void)n_in; (void)out_size;

  transpose_router<<<dim3(18944), dim3(256), 0, stream>>>(w1, w3, w2, w13t, w2t,
                                                          x, Wr, Pbuf, expert_sel, slot_w);
  offsets_kernel<<<dim3(1), dim3(256), 0, stream>>>(expert_sel, meta, Pbuf, outp + (size_t)T_TOK * D_DIM);
  assign_kernel<<<dim3(NSLOT / 256), dim3(256), 0, stream>>>(expert_sel, meta, slot_pos);
  gather_kernel<<<dim3(T_TOK / 4), dim3(256), 0, stream>>>(slot_pos, x, Xg);
  gemm1_kernel<<<dim3((2 * H_DIM / 256) * MT_MAX), dim3(256), 0, stream>>>(Xg, w13t, Hb, meta);
  gemm2_kernel<<<dim3((D_DIM / 256) * MT_MAX), dim3(256), 0, stream>>>(Hb, w2t, Y, meta);
  combine_kernel<<<dim3(T_TOK), dim3(256), 0, stream>>>(slot_pos, slot_w, Y, outp);
}

// Round 11
// 532.466 us; speedup vs baseline: 1.1138x; 1.0333x over previous
//
#include <hip/hip_runtime.h>
#include <hip/hip_bf16.h>
#include <stdint.h>

// MoE top-2 (T=8192, D=1024, H=2816, E=8) — sparse grouped-GEMM implementation.
// R11: both GEMMs -> 128x128 tiles (m103-proven best tile for 2-barrier
// structure; fixes gemm2's 544-tile tail quantization: 1088 tiles now).
// All non-GEMM kernels byte-identical to R10.

#define T_TOK 8192
#define D_DIM 1024
#define H_DIM 2816
#define E_EXP 8
#define NSLOT 16384       // T * 2
#define CAP_ROWS 18432
#define MT_MAX 136        // 128-row tiles

// meta int layout
#define MI_T2 1
#define MI_POS 8
#define MI_MTE2 16
#define MI_MTB2 (16 + MT_MAX)

typedef __attribute__((ext_vector_type(8))) short short8;
typedef __attribute__((ext_vector_type(4))) float f32x4;

#define GLD16(gsrc, ldst) __builtin_amdgcn_global_load_lds( \
    (const __attribute__((address_space(1))) void*)(gsrc),  \
    (__attribute__((address_space(3))) void*)(ldst), 16, 0, 0)

// ---------------- merged: weight transposes + router ----------------
// blocks [0, 11264): w13 interleaved transpose, (E,D,H)x2 -> (E,2H,D)
// blocks [11264, 16896): w2 transpose, (E,H,D) -> (E,D,H)
// blocks [16896, 18944): router (4 tokens/block)
__global__ __launch_bounds__(256) void transpose_router(const float* __restrict__ w1,
                                                        const float* __restrict__ w3,
                                                        const float* __restrict__ w2,
                                                        __hip_bfloat16* __restrict__ w13t,
                                                        __hip_bfloat16* __restrict__ w2t,
                                                        const float* __restrict__ x,
                                                        const float* __restrict__ Wr,
                                                        float* __restrict__ Pbuf,
                                                        int* __restrict__ expert_sel,
                                                        float* __restrict__ slot_w) {
  __shared__ float tile[64][65];
  __shared__ float sP[4][8];
  int bid = blockIdx.x, tid = threadIdx.x;
  int lc = (tid & 15) * 4;
  int lr = tid >> 4;
  if (bid < 11264) {
    int z = bid / 704, rem = bid % 704;
    int bx = rem % 44, by = rem / 44;
    int e = z >> 1, w3f = z & 1;
    const float* in = w3f ? w3 : w1;
    int h0 = bx * 64, d0 = by * 64;
    const float* src = in + ((size_t)e * D_DIM + d0) * H_DIM + h0;
#pragma unroll
    for (int i = 0; i < 4; i++) {
      float4 v = *(const float4*)(src + (size_t)(lr + i * 16) * H_DIM + lc);
      tile[lr + i * 16][lc + 0] = v.x;
      tile[lr + i * 16][lc + 1] = v.y;
      tile[lr + i * 16][lc + 2] = v.z;
      tile[lr + i * 16][lc + 3] = v.w;
    }
    __syncthreads();
    __hip_bfloat16* dstE = w13t + (size_t)e * (2 * H_DIM) * D_DIM;
    int rB = (tid & 7) * 8;  // d offset within tile
#pragma unroll
    for (int i = 0; i < 2; i++) {
      int hh = (tid >> 3) + i * 32;
      int habs = h0 + hh;
      int rw = 2 * (habs & ~15) + (habs & 15) + (w3f ? 16 : 0);
      __align__(16) __hip_bfloat16 o[8];
#pragma unroll
      for (int k = 0; k < 8; k++) o[k] = __float2bfloat16(tile[rB + k][hh]);
      *(short8*)(dstE + (size_t)rw * D_DIM + d0 + rB) = *(const short8*)o;
    }
  } else if (bid < 16896) {
    int b2 = bid - 11264;
    int e = b2 / 704, rem = b2 % 704;
    int bx = rem % 16, by = rem / 16;
    int c0 = bx * 64, r0 = by * 64;
    const float* src = w2 + ((size_t)e * H_DIM + r0) * D_DIM + c0;
#pragma unroll
    for (int i = 0; i < 4; i++) {
      float4 v = *(const float4*)(src + (size_t)(lr + i * 16) * D_DIM + lc);
      tile[lr + i * 16][lc + 0] = v.x;
      tile[lr + i * 16][lc + 1] = v.y;
      tile[lr + i * 16][lc + 2] = v.z;
      tile[lr + i * 16][lc + 3] = v.w;
    }
    __syncthreads();
    __hip_bfloat16* dst = w2t + ((size_t)e * D_DIM + c0) * H_DIM + r0;
    int rB = (tid & 7) * 8;
#pragma unroll
    for (int i = 0; i < 2; i++) {
      int c = (tid >> 3) + i * 32;
      __align__(16) __hip_bfloat16 o[8];
#pragma unroll
      for (int k = 0; k < 8; k++) o[k] = __float2bfloat16(tile[rB + k][c]);
      *(short8*)(dst + (size_t)c * H_DIM + rB) = *(const short8*)o;
    }
  } else {
    int rb = bid - 16896;
    int wave = tid >> 6, lane = tid & 63;
    int tok = rb * 4 + wave;
    const float* xr = x + (size_t)tok * D_DIM;
    float acc[8];
#pragma unroll
    for (int e = 0; e < 8; e++) acc[e] = 0.f;
    for (int d = lane; d < D_DIM; d += 64) {
      float xv = xr[d];
      const float4* w4 = (const float4*)(Wr + d * 8);
      float4 wa = w4[0], wb = w4[1];
      acc[0] += xv * wa.x; acc[1] += xv * wa.y; acc[2] += xv * wa.z; acc[3] += xv * wa.w;
      acc[4] += xv * wb.x; acc[5] += xv * wb.y; acc[6] += xv * wb.z; acc[7] += xv * wb.w;
    }
#pragma unroll
    for (int e = 0; e < 8; e++) {
#pragma unroll
      for (int off = 32; off >= 1; off >>= 1) acc[e] += __shfl_xor(acc[e], off);
    }
    float mx = acc[0];
#pragma unroll
    for (int e = 1; e < 8; e++) mx = fmaxf(mx, acc[e]);
    float p[8], s = 0.f;
#pragma unroll
    for (int e = 0; e < 8; e++) { p[e] = expf(acc[e] - mx); s += p[e]; }
    float inv = 1.f / s;
#pragma unroll
    for (int e = 0; e < 8; e++) p[e] *= inv;
    int i0 = 0;
#pragma unroll
    for (int e = 1; e < 8; e++) if (p[e] > p[i0]) i0 = e;
    int i1 = (i0 == 0) ? 1 : 0;
#pragma unroll
    for (int e = 0; e < 8; e++) if (e != i0 && p[e] > p[i1]) i1 = e;
    float wsum = p[i0] + p[i1];
    if (lane == 0) {
      expert_sel[tok * 2] = i0;
      expert_sel[tok * 2 + 1] = i1;
      slot_w[tok * 2] = p[i0] / wsum;
      slot_w[tok * 2 + 1] = p[i1] / wsum;
#pragma unroll
      for (int e = 0; e < 8; e++) sP[wave][e] = p[e];
    }
    __syncthreads();
    if (tid < 8)
      Pbuf[tid * 2048 + rb] = sP[0][tid] + sP[1][tid] + sP[2][tid] + sP[3][tid];
  }
}

// ---------------- offsets: histogram + tile list + aux loss ----------------
__global__ __launch_bounds__(256) void offsets_kernel(const int* __restrict__ expert_sel,
                                                      int* __restrict__ meta,
                                                      const float* __restrict__ Pbuf,
                                                      float* __restrict__ aux_out) {
  int t = threadIdx.x;
  unsigned long long pA = 0, pB = 0;
  for (int i = 0; i < 64; i++) {
    int e = expert_sel[i * 256 + t];
    if (e < 4) pA += 1ull << (e * 16);
    else       pB += 1ull << ((e - 4) * 16);
  }
#pragma unroll
  for (int off = 32; off >= 1; off >>= 1) {
    pA += __shfl_xor(pA, off);
    pB += __shfl_xor(pB, off);
  }
  __shared__ unsigned long long sA[4], sB[4];
  __shared__ float red[8][33];
  int wave = t >> 6, lane = t & 63;
  if (lane == 0) { sA[wave] = pA; sB[wave] = pB; }
  int ee = t >> 5, j = t & 31;
  float s = 0.f;
  for (int c = j; c < 2048; c += 32) s += Pbuf[ee * 2048 + c];
  red[ee][j] = s;
  __syncthreads();
  if (t == 0) {
    unsigned long long A = sA[0] + sA[1] + sA[2] + sA[3];
    unsigned long long B = sB[0] + sB[1] + sB[2] + sB[3];
    int cnt[8];
    for (int e = 0; e < 4; e++) cnt[e] = (int)((A >> (e * 16)) & 0xFFFF);
    for (int e = 0; e < 4; e++) cnt[4 + e] = (int)((B >> (e * 16)) & 0xFFFF);
    float psum[8];
    for (int e = 0; e < 8; e++) {
      float ss = 0.f;
      for (int k = 0; k < 32; k++) ss += red[e][k];
      psum[e] = ss;
    }
    int off = 0, n2 = 0;
    float aux = 0.f;
    for (int e = 0; e < 8; e++) {
      int c = cnt[e];
      meta[MI_POS + e] = off;
      int t2 = (c + 127) >> 7;
      for (int jj = 0; jj < t2; jj++) { meta[MI_MTE2 + n2] = e; meta[MI_MTB2 + n2] = off + jj * 128; n2++; }
      off += t2 * 128;
      aux += ((float)c / 16384.f) * (psum[e] / 8192.f);
    }
    meta[MI_T2] = n2;
    *aux_out = 8.f * aux;
  }
}

// ---------------- assign: ballot-aggregated positions ----------------
__global__ __launch_bounds__(256) void assign_kernel(const int* __restrict__ expert_sel,
                                                     int* __restrict__ meta,
                                                     int* __restrict__ slot_pos) {
  int tid = threadIdx.x, wave = tid >> 6, lane = tid & 63;
  int slot = blockIdx.x * 256 + tid;
  int e = expert_sel[slot];
  __shared__ int cnt[4][8];
  __shared__ int base[8];
  __shared__ int woff[4][8];
  int rank = 0;
#pragma unroll
  for (int ee = 0; ee < 8; ee++) {
    unsigned long long msk = __ballot(e == ee);
    if (lane == 0) cnt[wave][ee] = __popcll(msk);
    if (e == ee) rank = __popcll(msk & ((1ull << lane) - 1ull));
  }
  __syncthreads();
  if (tid < 8) {
    int c0 = cnt[0][tid], c1 = cnt[1][tid], c2 = cnt[2][tid], c3 = cnt[3][tid];
    int tot = c0 + c1 + c2 + c3;
    base[tid] = atomicAdd(&meta[MI_POS + tid], tot);
    woff[0][tid] = 0; woff[1][tid] = c0; woff[2][tid] = c0 + c1; woff[3][tid] = c0 + c1 + c2;
  }
  __syncthreads();
  slot_pos[slot] = base[e] + woff[wave][e] + rank;
}

// ---------------- gather: one read per token, write both slots ----------------
__global__ __launch_bounds__(256) void gather_kernel(const int* __restrict__ slot_pos,
                                                     const float* __restrict__ x,
                                                     __hip_bfloat16* __restrict__ Xg) {
  int wave = threadIdx.x >> 6, lane = threadIdx.x & 63;
  int tok = blockIdx.x * 4 + wave;
  int p0 = slot_pos[tok * 2], p1 = slot_pos[tok * 2 + 1];
  const float4* src = (const float4*)(x + (size_t)tok * D_DIM);
  __hip_bfloat16* d0 = Xg + (size_t)p0 * D_DIM;
  __hip_bfloat16* d1 = Xg + (size_t)p1 * D_DIM;
#pragma unroll
  for (int p = 0; p < 4; p++) {
    float4 v = src[p * 64 + lane];
    union { ushort4 u4; __hip_bfloat16 h[4]; } cv;
    cv.h[0] = __float2bfloat16(v.x);
    cv.h[1] = __float2bfloat16(v.y);
    cv.h[2] = __float2bfloat16(v.z);
    cv.h[3] = __float2bfloat16(v.w);
    *(ushort4*)(d0 + (p * 64 + lane) * 4) = cv.u4;
    *(ushort4*)(d1 + (p * 64 + lane) * 4) = cv.u4;
  }
}

// ---------------- GEMM helpers (BK=64) ----------------
__device__ __forceinline__ short8 frag_read64(const char* tile, int row, int gk) {
  int byte = (row << 7) | ((gk ^ (row & 7)) << 4);
  return *(const short8*)(tile + byte);
}

template <int NITER, int BLK>
__device__ __forceinline__ void stage_rowsT(const __hip_bfloat16* gbase, int ld, char* tile,
                                            int tid) {
#pragma unroll
  for (int i = 0; i < NITER; i++) {
    int L = i * (BLK * 16) + tid * 16;
    int row = L >> 7;
    int g = (L >> 4) & 7;
    int gs = g ^ (row & 7);  // pre-swizzled global source, linear LDS dest
    const char* src = (const char*)(gbase + (size_t)row * ld) + gs * 16;
    GLD16(src, tile + i * (BLK * 16) + (tid >> 6) * 1024);
  }
}

__device__ __forceinline__ void tile_from_bid(int bid, int nwg, int mmax, int* m, int* n) {
  int cpx = nwg >> 3;
  int u = (bid & 7) * cpx + (bid >> 3);
  *n = u / mmax;
  *m = u % mmax;
}

// ---------------- GEMM1: Hb = silu/fuse( Xg @ w13t^T ), 128x(128 interleaved) ----------------
__global__ __launch_bounds__(256, 2) void gemm1_kernel(const __hip_bfloat16* __restrict__ Xg,
                                                       const __hip_bfloat16* __restrict__ w13t,
                                                       __hip_bfloat16* __restrict__ Hb,
                                                       const int* __restrict__ meta) {
  int m, nIdx;
  tile_from_bid(blockIdx.x, (2 * H_DIM / 128) * MT_MAX, MT_MAX, &m, &nIdx);
  if (m >= meta[MI_T2]) return;
  int e = meta[MI_MTE2 + m];
  int row0 = meta[MI_MTB2 + m];
  int n0 = nIdx * 128;  // interleaved-row offset (= 64 h-cols)
  __shared__ __align__(16) char ldsA[16384];
  __shared__ __align__(16) char ldsB[16384];
  int tid = threadIdx.x, wave = tid >> 6, lane = tid & 63;
  int wr = wave >> 1, wc = wave & 1;
  const __hip_bfloat16* Ab = Xg + (size_t)row0 * D_DIM;
  const __hip_bfloat16* Bb = w13t + ((size_t)e * (2 * H_DIM) + n0) * D_DIM;

  f32x4 acc[4][4];
#pragma unroll
  for (int i = 0; i < 4; i++)
#pragma unroll
    for (int j = 0; j < 4; j++) acc[i][j] = 0.f;

  int rsel = lane & 15, kg = lane >> 4;
  for (int k0 = 0; k0 < D_DIM; k0 += 64) {
    stage_rowsT<4, 256>(Ab + k0, D_DIM, ldsA, tid);
    stage_rowsT<4, 256>(Bb + k0, D_DIM, ldsB, tid);
    asm volatile("s_waitcnt vmcnt(0)" ::: "memory");
    __syncthreads();
#pragma unroll
    for (int kk = 0; kk < 2; kk++) {
      int gk = kk * 4 + kg;
      short8 a[4], b[4];
#pragma unroll
      for (int f = 0; f < 4; f++) a[f] = frag_read64(ldsA, wr * 64 + f * 16 + rsel, gk);
#pragma unroll
      for (int f = 0; f < 4; f++) b[f] = frag_read64(ldsB, wc * 64 + f * 16 + rsel, gk);
#pragma unroll
      for (int fm = 0; fm < 4; fm++)
#pragma unroll
        for (int fn = 0; fn < 4; fn++)
          acc[fm][fn] = __builtin_amdgcn_mfma_f32_16x16x32_bf16(a[fm], b[fn], acc[fm][fn], 0, 0, 0);
    }
    __syncthreads();
  }
  int rq = lane >> 4;
#pragma unroll
  for (int fm = 0; fm < 4; fm++)
#pragma unroll
    for (int fnp = 0; fnp < 2; fnp++)
#pragma unroll
      for (int j = 0; j < 4; j++) {
        float v1 = acc[fm][2 * fnp][j], v3 = acc[fm][2 * fnp + 1][j];
        float h = (v1 / (1.f + expf(-v1))) * v3;  // silu(v1)*v3
        int r = row0 + wr * 64 + fm * 16 + rq * 4 + j;
        int c = (n0 >> 1) + wc * 32 + fnp * 16 + rsel;
        Hb[(size_t)r * H_DIM + c] = __float2bfloat16(h);
      }
}

// ---------------- GEMM2: Y = Hb @ w2t^T (bf16 out), 128x128 tile ----------------
__global__ __launch_bounds__(256, 2) void gemm2_kernel(const __hip_bfloat16* __restrict__ Hb,
                                                       const __hip_bfloat16* __restrict__ w2t,
                                                       __hip_bfloat16* __restrict__ Y,
                                                       const int* __restrict__ meta) {
  int m, nIdx;
  tile_from_bid(blockIdx.x, (D_DIM / 128) * MT_MAX, MT_MAX, &m, &nIdx);
  if (m >= meta[MI_T2]) return;
  int e = meta[MI_MTE2 + m];
  int row0 = meta[MI_MTB2 + m];
  int n0 = nIdx * 128;
  __shared__ __align__(16) char ldsA[16384];
  __shared__ __align__(16) char ldsB[16384];
  int tid = threadIdx.x, wave = tid >> 6, lane = tid & 63;
  int wr = wave >> 1, wc = wave & 1;
  const __hip_bfloat16* Ab = Hb + (size_t)row0 * H_DIM;
  const __hip_bfloat16* Bb = w2t + ((size_t)e * D_DIM + n0) * H_DIM;

  f32x4 acc[4][4];
#pragma unroll
  for (int i = 0; i < 4; i++)
#pragma unroll
    for (int j = 0; j < 4; j++) acc[i][j] = 0.f;

  int rsel = lane & 15, kg = lane >> 4;
  for (int k0 = 0; k0 < H_DIM; k0 += 64) {
    stage_rowsT<4, 256>(Ab + k0, H_DIM, ldsA, tid);
    stage_rowsT<4, 256>(Bb + k0, H_DIM, ldsB, tid);
    asm volatile("s_waitcnt vmcnt(0)" ::: "memory");
    __syncthreads();
#pragma unroll
    for (int kk = 0; kk < 2; kk++) {
      int gk = kk * 4 + kg;
      short8 a[4], b[4];
#pragma unroll
      for (int f = 0; f < 4; f++) a[f] = frag_read64(ldsA, wr * 64 + f * 16 + rsel, gk);
#pragma unroll
      for (int f = 0; f < 4; f++) b[f] = frag_read64(ldsB, wc * 64 + f * 16 + rsel, gk);
#pragma unroll
      for (int fm = 0; fm < 4; fm++)
#pragma unroll
        for (int fn = 0; fn < 4; fn++)
          acc[fm][fn] = __builtin_amdgcn_mfma_f32_16x16x32_bf16(a[fm], b[fn], acc[fm][fn], 0, 0, 0);
    }
    __syncthreads();
  }
  int rq = lane >> 4;
#pragma unroll
  for (int fm = 0; fm < 4; fm++)
#pragma unroll
    for (int fn = 0; fn < 4; fn++)
#pragma unroll
      for (int j = 0; j < 4; j++) {
        int r = row0 + wr * 64 + fm * 16 + rq * 4 + j;
        int c = n0 + wc * 64 + fn * 16 + rsel;
        Y[(size_t)r * D_DIM + c] = __float2bfloat16(acc[fm][fn][j]);
      }
}

// ---------------- combine: out[t] = w0*Y[p0] + w1*Y[p1] (bf16 Y) ----------------
__global__ __launch_bounds__(256) void combine_kernel(const int* __restrict__ slot_pos,
                                                      const float* __restrict__ slot_w,
                                                      const __hip_bfloat16* __restrict__ Y,
                                                      float* __restrict__ outp) {
  int tok = blockIdx.x;
  int p0 = slot_pos[tok * 2], p1 = slot_pos[tok * 2 + 1];
  float w0 = slot_w[tok * 2], w1 = slot_w[tok * 2 + 1];
  int i4 = threadIdx.x;  // 256 threads x 4 elems
  ushort4 a = *(const ushort4*)(Y + (size_t)p0 * D_DIM + i4 * 4);
  ushort4 b = *(const ushort4*)(Y + (size_t)p1 * D_DIM + i4 * 4);
  union { ushort u; __hip_bfloat16 h; } c0, c1;
  float4 r;
  c0.u = a.x; c1.u = b.x; r.x = w0 * __bfloat162float(c0.h) + w1 * __bfloat162float(c1.h);
  c0.u = a.y; c1.u = b.y; r.y = w0 * __bfloat162float(c0.h) + w1 * __bfloat162float(c1.h);
  c0.u = a.z; c1.u = b.z; r.z = w0 * __bfloat162float(c0.h) + w1 * __bfloat162float(c1.h);
  c0.u = a.w; c1.u = b.w; r.w = w0 * __bfloat162float(c0.h) + w1 * __bfloat162float(c1.h);
  ((float4*)(outp + (size_t)tok * D_DIM))[i4] = r;
}

// ---------------- launch ----------------
extern "C" void kernel_launch(void* const* d_in, const int* in_sizes, int n_in,
                              void* d_out, int out_size, void* d_ws, size_t ws_size,
                              hipStream_t stream) {
  const float* x = (const float*)d_in[0];
  const float* Wr = (const float*)d_in[1];
  const float* w1 = (const float*)d_in[2];
  const float* w3 = (const float*)d_in[3];
  const float* w2 = (const float*)d_in[4];
  float* outp = (float*)d_out;

  char* ws = (char*)d_ws;
  size_t off = 0;
  auto alloc = [&](size_t bytes) -> char* {
    char* p = ws + off;
    off += (bytes + 255) & ~(size_t)255;
    return p;
  };
  __hip_bfloat16* w13t = (__hip_bfloat16*)alloc((size_t)E_EXP * 2 * H_DIM * D_DIM * 2);
  __hip_bfloat16* w2t = (__hip_bfloat16*)alloc((size_t)E_EXP * D_DIM * H_DIM * 2);
  __hip_bfloat16* Xg = (__hip_bfloat16*)alloc((size_t)CAP_ROWS * D_DIM * 2);
  __hip_bfloat16* Hb = (__hip_bfloat16*)alloc((size_t)CAP_ROWS * H_DIM * 2);
  __hip_bfloat16* Y = (__hip_bfloat16*)alloc((size_t)CAP_ROWS * D_DIM * 2);
  float* slot_w = (float*)alloc(NSLOT * 4);
  int* slot_pos = (int*)alloc(NSLOT * 4);
  int* expert_sel = (int*)alloc(NSLOT * 4);
  float* Pbuf = (float*)alloc(2048 * 8 * 4);
  int* meta = (int*)alloc(2048);
  (void)ws_size; (void)in_sizes; (void)n_in; (void)out_size;

  transpose_router<<<dim3(18944), dim3(256), 0, stream>>>(w1, w3, w2, w13t, w2t,
                                                          x, Wr, Pbuf, expert_sel, slot_w);
  offsets_kernel<<<dim3(1), dim3(256), 0, stream>>>(expert_sel, meta, Pbuf, outp + (size_t)T_TOK * D_DIM);
  assign_kernel<<<dim3(NSLOT / 256), dim3(256), 0, stream>>>(expert_sel, meta, slot_pos);
  gather_kernel<<<dim3(T_TOK / 4), dim3(256), 0, stream>>>(slot_pos, x, Xg);
  gemm1_kernel<<<dim3((2 * H_DIM / 128) * MT_MAX), dim3(256), 0, stream>>>(Xg, w13t, Hb, meta);
  gemm2_kernel<<<dim3((D_DIM / 128) * MT_MAX), dim3(256), 0, stream>>>(Hb, w2t, Y, meta);
  combine_kernel<<<dim3(T_TOK), dim3(256), 0, stream>>>(slot_pos, slot_w, Y, outp);
}

// Round 12
// 511.586 us; speedup vs baseline: 1.1592x; 1.0408x over previous
//
#include <hip/hip_runtime.h>
#include <hip/hip_bf16.h>
#include <stdint.h>

// MoE top-2 (T=8192, D=1024, H=2816, E=8) — sparse grouped-GEMM implementation.
// R12: 5 dispatches. Router writes non-duplicated bf16 Xb; gemm1 stages A via
// tok_of_pos indirection (no gather kernel). Assign is self-sufficient
// (full+prefix histogram, no offsets kernel, no atomics); GEMMs derive
// (expert,row0) from cnt[8]. GEMM cores unchanged from R11 (128x128, BK=64).

#define T_TOK 8192
#define D_DIM 1024
#define H_DIM 2816
#define E_EXP 8
#define NSLOT 16384       // T * 2
#define CAP_ROWS 18432
#define MT_MAX 136        // 128-row tiles

typedef __attribute__((ext_vector_type(8))) short short8;
typedef __attribute__((ext_vector_type(4))) float f32x4;

#define GLD16(gsrc, ldst) __builtin_amdgcn_global_load_lds( \
    (const __attribute__((address_space(1))) void*)(gsrc),  \
    (__attribute__((address_space(3))) void*)(ldst), 16, 0, 0)

// ---------------- merged: weight transposes + router (+Xb bf16 write) ----------------
// blocks [0, 11264): w13 interleaved transpose, (E,D,H)x2 -> (E,2H,D)
// blocks [11264, 16896): w2 transpose, (E,H,D) -> (E,D,H)
// blocks [16896, 18944): router (4 tokens/block) + x->bf16 row conversion
__global__ __launch_bounds__(256) void transpose_router(const float* __restrict__ w1,
                                                        const float* __restrict__ w3,
                                                        const float* __restrict__ w2,
                                                        __hip_bfloat16* __restrict__ w13t,
                                                        __hip_bfloat16* __restrict__ w2t,
                                                        const float* __restrict__ x,
                                                        const float* __restrict__ Wr,
                                                        float* __restrict__ Pbuf,
                                                        int* __restrict__ expert_sel,
                                                        float* __restrict__ slot_w,
                                                        __hip_bfloat16* __restrict__ Xb) {
  __shared__ float tile[64][65];
  __shared__ float sP[4][8];
  int bid = blockIdx.x, tid = threadIdx.x;
  int lc = (tid & 15) * 4;
  int lr = tid >> 4;
  if (bid < 11264) {
    int z = bid / 704, rem = bid % 704;
    int bx = rem % 44, by = rem / 44;
    int e = z >> 1, w3f = z & 1;
    const float* in = w3f ? w3 : w1;
    int h0 = bx * 64, d0 = by * 64;
    const float* src = in + ((size_t)e * D_DIM + d0) * H_DIM + h0;
#pragma unroll
    for (int i = 0; i < 4; i++) {
      float4 v = *(const float4*)(src + (size_t)(lr + i * 16) * H_DIM + lc);
      tile[lr + i * 16][lc + 0] = v.x;
      tile[lr + i * 16][lc + 1] = v.y;
      tile[lr + i * 16][lc + 2] = v.z;
      tile[lr + i * 16][lc + 3] = v.w;
    }
    __syncthreads();
    __hip_bfloat16* dstE = w13t + (size_t)e * (2 * H_DIM) * D_DIM;
    int rB = (tid & 7) * 8;  // d offset within tile
#pragma unroll
    for (int i = 0; i < 2; i++) {
      int hh = (tid >> 3) + i * 32;
      int habs = h0 + hh;
      int rw = 2 * (habs & ~15) + (habs & 15) + (w3f ? 16 : 0);
      __align__(16) __hip_bfloat16 o[8];
#pragma unroll
      for (int k = 0; k < 8; k++) o[k] = __float2bfloat16(tile[rB + k][hh]);
      *(short8*)(dstE + (size_t)rw * D_DIM + d0 + rB) = *(const short8*)o;
    }
  } else if (bid < 16896) {
    int b2 = bid - 11264;
    int e = b2 / 704, rem = b2 % 704;
    int bx = rem % 16, by = rem / 16;
    int c0 = bx * 64, r0 = by * 64;
    const float* src = w2 + ((size_t)e * H_DIM + r0) * D_DIM + c0;
#pragma unroll
    for (int i = 0; i < 4; i++) {
      float4 v = *(const float4*)(src + (size_t)(lr + i * 16) * D_DIM + lc);
      tile[lr + i * 16][lc + 0] = v.x;
      tile[lr + i * 16][lc + 1] = v.y;
      tile[lr + i * 16][lc + 2] = v.z;
      tile[lr + i * 16][lc + 3] = v.w;
    }
    __syncthreads();
    __hip_bfloat16* dst = w2t + ((size_t)e * D_DIM + c0) * H_DIM + r0;
    int rB = (tid & 7) * 8;
#pragma unroll
    for (int i = 0; i < 2; i++) {
      int c = (tid >> 3) + i * 32;
      __align__(16) __hip_bfloat16 o[8];
#pragma unroll
      for (int k = 0; k < 8; k++) o[k] = __float2bfloat16(tile[rB + k][c]);
      *(short8*)(dst + (size_t)c * H_DIM + rB) = *(const short8*)o;
    }
  } else {
    int rb = bid - 16896;
    int wave = tid >> 6, lane = tid & 63;
    int tok = rb * 4 + wave;
    const float* xr = x + (size_t)tok * D_DIM;
    float acc[8];
#pragma unroll
    for (int e = 0; e < 8; e++) acc[e] = 0.f;
    for (int d = lane; d < D_DIM; d += 64) {
      float xv = xr[d];
      const float4* w4 = (const float4*)(Wr + d * 8);
      float4 wa = w4[0], wb = w4[1];
      acc[0] += xv * wa.x; acc[1] += xv * wa.y; acc[2] += xv * wa.z; acc[3] += xv * wa.w;
      acc[4] += xv * wb.x; acc[5] += xv * wb.y; acc[6] += xv * wb.z; acc[7] += xv * wb.w;
    }
    // x row -> bf16 Xb (for gemm1 indirect A staging)
    const float4* xr4 = (const float4*)xr;
    __hip_bfloat16* xbr = Xb + (size_t)tok * D_DIM;
#pragma unroll
    for (int p = 0; p < 4; p++) {
      float4 v = xr4[p * 64 + lane];
      union { ushort4 u4; __hip_bfloat16 h[4]; } cv;
      cv.h[0] = __float2bfloat16(v.x);
      cv.h[1] = __float2bfloat16(v.y);
      cv.h[2] = __float2bfloat16(v.z);
      cv.h[3] = __float2bfloat16(v.w);
      *(ushort4*)(xbr + (p * 64 + lane) * 4) = cv.u4;
    }
#pragma unroll
    for (int e = 0; e < 8; e++) {
#pragma unroll
      for (int off = 32; off >= 1; off >>= 1) acc[e] += __shfl_xor(acc[e], off);
    }
    float mx = acc[0];
#pragma unroll
    for (int e = 1; e < 8; e++) mx = fmaxf(mx, acc[e]);
    float p[8], s = 0.f;
#pragma unroll
    for (int e = 0; e < 8; e++) { p[e] = expf(acc[e] - mx); s += p[e]; }
    float inv = 1.f / s;
#pragma unroll
    for (int e = 0; e < 8; e++) p[e] *= inv;
    int i0 = 0;
#pragma unroll
    for (int e = 1; e < 8; e++) if (p[e] > p[i0]) i0 = e;
    int i1 = (i0 == 0) ? 1 : 0;
#pragma unroll
    for (int e = 0; e < 8; e++) if (e != i0 && p[e] > p[i1]) i1 = e;
    float wsum = p[i0] + p[i1];
    if (lane == 0) {
      expert_sel[tok * 2] = i0;
      expert_sel[tok * 2 + 1] = i1;
      slot_w[tok * 2] = p[i0] / wsum;
      slot_w[tok * 2 + 1] = p[i1] / wsum;
#pragma unroll
      for (int e = 0; e < 8; e++) sP[wave][e] = p[e];
    }
    __syncthreads();
    if (tid < 8)
      Pbuf[tid * 2048 + rb] = sP[0][tid] + sP[1][tid] + sP[2][tid] + sP[3][tid];
  }
}

// ---------------- assign: self-sufficient (full+prefix histograms, no atomics) ----------------
// Also: block 0 writes cnt[8] and aux loss.
__global__ __launch_bounds__(256) void assign_kernel(const int* __restrict__ expert_sel,
                                                     const float* __restrict__ Pbuf,
                                                     int* __restrict__ slot_pos,
                                                     int* __restrict__ tok_of_pos,
                                                     int* __restrict__ cnt_out,
                                                     float* __restrict__ aux_out) {
  __shared__ unsigned long long sF[2][4], sQ[2][4];
  __shared__ int wcnt[4][8];
  __shared__ int woff[4][8];
  __shared__ float red[8][33];
  int b = blockIdx.x, tid = threadIdx.x, wave = tid >> 6, lane = tid & 63;
  int myslot = b * 256 + tid;
  int mye = expert_sel[myslot];

  // full (f) and prefix (<b*256) (q) histograms, 16-bit packed in 2 ULLs
  unsigned long long fA = 0, fB = 0, qA = 0, qB = 0;
  int lim = b * 256;
  for (int i = tid; i < NSLOT; i += 256) {
    int e = expert_sel[i];
    if (e < 4) {
      unsigned long long inc = 1ull << (e * 16);
      fA += inc; if (i < lim) qA += inc;
    } else {
      unsigned long long inc = 1ull << ((e - 4) * 16);
      fB += inc; if (i < lim) qB += inc;
    }
  }
#pragma unroll
  for (int off = 32; off >= 1; off >>= 1) {
    fA += __shfl_xor(fA, off); fB += __shfl_xor(fB, off);
    qA += __shfl_xor(qA, off); qB += __shfl_xor(qB, off);
  }
  if (lane == 0) { sF[0][wave] = fA; sF[1][wave] = fB; sQ[0][wave] = qA; sQ[1][wave] = qB; }
  // intra-wave rank + per-wave counts for this block's slots
  int rank = 0;
#pragma unroll
  for (int ee = 0; ee < 8; ee++) {
    unsigned long long msk = __ballot(mye == ee);
    if (lane == 0) wcnt[wave][ee] = __popcll(msk);
    if (mye == ee) rank = __popcll(msk & ((1ull << lane) - 1ull));
  }
  __syncthreads();
  unsigned long long FA = sF[0][0] + sF[0][1] + sF[0][2] + sF[0][3];
  unsigned long long FB = sF[1][0] + sF[1][1] + sF[1][2] + sF[1][3];
  unsigned long long QA = sQ[0][0] + sQ[0][1] + sQ[0][2] + sQ[0][3];
  unsigned long long QB = sQ[1][0] + sQ[1][1] + sQ[1][2] + sQ[1][3];
  int cnt[8], pre[8];
#pragma unroll
  for (int e2 = 0; e2 < 4; e2++) {
    cnt[e2] = (int)((FA >> (e2 * 16)) & 0xFFFF);
    pre[e2] = (int)((QA >> (e2 * 16)) & 0xFFFF);
    cnt[4 + e2] = (int)((FB >> (e2 * 16)) & 0xFFFF);
    pre[4 + e2] = (int)((QB >> (e2 * 16)) & 0xFFFF);
  }
  if (tid < 8) {
    int c0 = wcnt[0][tid], c1 = wcnt[1][tid], c2 = wcnt[2][tid];
    woff[0][tid] = 0; woff[1][tid] = c0; woff[2][tid] = c0 + c1; woff[3][tid] = c0 + c1 + c2;
    if (b == 0) cnt_out[tid] = cnt[tid];
  }
  __syncthreads();
  // pos base: tile-aligned prefix over experts < mye
  int pb = 0;
#pragma unroll
  for (int e2 = 0; e2 < 8; e2++)
    if (e2 < mye) pb += ((cnt[e2] + 127) >> 7) << 7;
  int pos = pb + pre[mye] + woff[wave][mye] + rank;
  slot_pos[myslot] = pos;
  tok_of_pos[pos] = myslot >> 1;

  if (b == 0) {  // aux loss
    int ee = tid >> 5, j = tid & 31;
    float s = 0.f;
    for (int c = j; c < 2048; c += 32) s += Pbuf[ee * 2048 + c];
    red[ee][j] = s;
    __syncthreads();
    if (tid == 0) {
      float aux = 0.f;
      for (int e2 = 0; e2 < 8; e2++) {
        float ss = 0.f;
        for (int k = 0; k < 32; k++) ss += red[e2][k];
        aux += ((float)cnt[e2] / 16384.f) * (ss / 8192.f);
      }
      *aux_out = 8.f * aux;
    }
  }
}

// ---------------- GEMM helpers (BK=64) ----------------
__device__ __forceinline__ short8 frag_read64(const char* tile, int row, int gk) {
  int byte = (row << 7) | ((gk ^ (row & 7)) << 4);
  return *(const short8*)(tile + byte);
}

template <int NITER, int BLK>
__device__ __forceinline__ void stage_rowsT(const __hip_bfloat16* gbase, int ld, char* tile,
                                            int tid) {
#pragma unroll
  for (int i = 0; i < NITER; i++) {
    int L = i * (BLK * 16) + tid * 16;
    int row = L >> 7;
    int g = (L >> 4) & 7;
    int gs = g ^ (row & 7);  // pre-swizzled global source, linear LDS dest
    const char* src = (const char*)(gbase + (size_t)row * ld) + gs * 16;
    GLD16(src, tile + i * (BLK * 16) + (tid >> 6) * 1024);
  }
}

__device__ __forceinline__ void tile_from_bid(int bid, int nwg, int mmax, int* m, int* n) {
  int cpx = nwg >> 3;
  int u = (bid & 7) * cpx + (bid >> 3);
  *n = u / mmax;
  *m = u % mmax;
}

// expert of tile m (tiles are 128-row aligned; row0 = m*128); -1 if beyond total
__device__ __forceinline__ int expert_of_tile(const int* __restrict__ cnt, int m) {
  int acc = 0, e = -1;
#pragma unroll
  for (int ee = 0; ee < 8; ee++) {
    int t = (cnt[ee] + 127) >> 7;
    if (e < 0 && m < acc + t) e = ee;
    acc += t;
  }
  return e;
}

// ---------------- GEMM1: Hb = silu/fuse( Xb[tok] @ w13t^T ), 128x(128 interleaved) ----------------
__global__ __launch_bounds__(256, 2) void gemm1_kernel(const __hip_bfloat16* __restrict__ Xb,
                                                       const __hip_bfloat16* __restrict__ w13t,
                                                       __hip_bfloat16* __restrict__ Hb,
                                                       const int* __restrict__ tok_of_pos,
                                                       const int* __restrict__ cnt) {
  int m, nIdx;
  tile_from_bid(blockIdx.x, (2 * H_DIM / 128) * MT_MAX, MT_MAX, &m, &nIdx);
  int e = expert_of_tile(cnt, m);
  if (e < 0) return;
  int row0 = m * 128;
  int n0 = nIdx * 128;  // interleaved-row offset (= 64 h-cols)
  __shared__ __align__(16) char ldsA[16384];
  __shared__ __align__(16) char ldsB[16384];
  int tid = threadIdx.x, wave = tid >> 6, lane = tid & 63;
  int wr = wave >> 1, wc = wave & 1;
  const __hip_bfloat16* Bb = w13t + ((size_t)e * (2 * H_DIM) + n0) * D_DIM;

  // per-thread token-indirected A source bases (4 staged rows/thread, fixed)
  const char* srcA[4];
#pragma unroll
  for (int i = 0; i < 4; i++) {
    int row = i * 32 + (tid >> 3);
    int gs = (tid & 7) ^ (row & 7);
    int tk = tok_of_pos[row0 + row] & (T_TOK - 1);  // mask keeps pad rows in-bounds
    srcA[i] = (const char*)(Xb + (size_t)tk * D_DIM) + gs * 16;
  }

  f32x4 acc[4][4];
#pragma unroll
  for (int i = 0; i < 4; i++)
#pragma unroll
    for (int j = 0; j < 4; j++) acc[i][j] = 0.f;

  int rsel = lane & 15, kg = lane >> 4;
  for (int k0 = 0; k0 < D_DIM; k0 += 64) {
#pragma unroll
    for (int i = 0; i < 4; i++)
      GLD16(srcA[i] + (size_t)k0 * 2, ldsA + i * 4096 + wave * 1024);
    stage_rowsT<4, 256>(Bb + k0, D_DIM, ldsB, tid);
    asm volatile("s_waitcnt vmcnt(0)" ::: "memory");
    __syncthreads();
#pragma unroll
    for (int kk = 0; kk < 2; kk++) {
      int gk = kk * 4 + kg;
      short8 a[4], b[4];
#pragma unroll
      for (int f = 0; f < 4; f++) a[f] = frag_read64(ldsA, wr * 64 + f * 16 + rsel, gk);
#pragma unroll
      for (int f = 0; f < 4; f++) b[f] = frag_read64(ldsB, wc * 64 + f * 16 + rsel, gk);
#pragma unroll
      for (int fm = 0; fm < 4; fm++)
#pragma unroll
        for (int fn = 0; fn < 4; fn++)
          acc[fm][fn] = __builtin_amdgcn_mfma_f32_16x16x32_bf16(a[fm], b[fn], acc[fm][fn], 0, 0, 0);
    }
    __syncthreads();
  }
  int rq = lane >> 4;
#pragma unroll
  for (int fm = 0; fm < 4; fm++)
#pragma unroll
    for (int fnp = 0; fnp < 2; fnp++)
#pragma unroll
      for (int j = 0; j < 4; j++) {
        float v1 = acc[fm][2 * fnp][j], v3 = acc[fm][2 * fnp + 1][j];
        float h = (v1 / (1.f + expf(-v1))) * v3;  // silu(v1)*v3
        int r = row0 + wr * 64 + fm * 16 + rq * 4 + j;
        int c = (n0 >> 1) + wc * 32 + fnp * 16 + rsel;
        Hb[(size_t)r * H_DIM + c] = __float2bfloat16(h);
      }
}

// ---------------- GEMM2: Y = Hb @ w2t^T (bf16 out), 128x128 tile ----------------
__global__ __launch_bounds__(256, 2) void gemm2_kernel(const __hip_bfloat16* __restrict__ Hb,
                                                       const __hip_bfloat16* __restrict__ w2t,
                                                       __hip_bfloat16* __restrict__ Y,
                                                       const int* __restrict__ cnt) {
  int m, nIdx;
  tile_from_bid(blockIdx.x, (D_DIM / 128) * MT_MAX, MT_MAX, &m, &nIdx);
  int e = expert_of_tile(cnt, m);
  if (e < 0) return;
  int row0 = m * 128;
  int n0 = nIdx * 128;
  __shared__ __align__(16) char ldsA[16384];
  __shared__ __align__(16) char ldsB[16384];
  int tid = threadIdx.x, wave = tid >> 6, lane = tid & 63;
  int wr = wave >> 1, wc = wave & 1;
  const __hip_bfloat16* Ab = Hb + (size_t)row0 * H_DIM;
  const __hip_bfloat16* Bb = w2t + ((size_t)e * D_DIM + n0) * H_DIM;

  f32x4 acc[4][4];
#pragma unroll
  for (int i = 0; i < 4; i++)
#pragma unroll
    for (int j = 0; j < 4; j++) acc[i][j] = 0.f;

  int rsel = lane & 15, kg = lane >> 4;
  for (int k0 = 0; k0 < H_DIM; k0 += 64) {
    stage_rowsT<4, 256>(Ab + k0, H_DIM, ldsA, tid);
    stage_rowsT<4, 256>(Bb + k0, H_DIM, ldsB, tid);
    asm volatile("s_waitcnt vmcnt(0)" ::: "memory");
    __syncthreads();
#pragma unroll
    for (int kk = 0; kk < 2; kk++) {
      int gk = kk * 4 + kg;
      short8 a[4], b[4];
#pragma unroll
      for (int f = 0; f < 4; f++) a[f] = frag_read64(ldsA, wr * 64 + f * 16 + rsel, gk);
#pragma unroll
      for (int f = 0; f < 4; f++) b[f] = frag_read64(ldsB, wc * 64 + f * 16 + rsel, gk);
#pragma unroll
      for (int fm = 0; fm < 4; fm++)
#pragma unroll
        for (int fn = 0; fn < 4; fn++)
          acc[fm][fn] = __builtin_amdgcn_mfma_f32_16x16x32_bf16(a[fm], b[fn], acc[fm][fn], 0, 0, 0);
    }
    __syncthreads();
  }
  int rq = lane >> 4;
#pragma unroll
  for (int fm = 0; fm < 4; fm++)
#pragma unroll
    for (int fn = 0; fn < 4; fn++)
#pragma unroll
      for (int j = 0; j < 4; j++) {
        int r = row0 + wr * 64 + fm * 16 + rq * 4 + j;
        int c = n0 + wc * 64 + fn * 16 + rsel;
        Y[(size_t)r * D_DIM + c] = __float2bfloat16(acc[fm][fn][j]);
      }
}

// ---------------- combine: out[t] = w0*Y[p0] + w1*Y[p1] (bf16 Y) ----------------
__global__ __launch_bounds__(256) void combine_kernel(const int* __restrict__ slot_pos,
                                                      const float* __restrict__ slot_w,
                                                      const __hip_bfloat16* __restrict__ Y,
                                                      float* __restrict__ outp) {
  int tok = blockIdx.x;
  int p0 = slot_pos[tok * 2], p1 = slot_pos[tok * 2 + 1];
  float w0 = slot_w[tok * 2], w1 = slot_w[tok * 2 + 1];
  int i4 = threadIdx.x;  // 256 threads x 4 elems
  ushort4 a = *(const ushort4*)(Y + (size_t)p0 * D_DIM + i4 * 4);
  ushort4 b = *(const ushort4*)(Y + (size_t)p1 * D_DIM + i4 * 4);
  union { ushort u; __hip_bfloat16 h; } c0, c1;
  float4 r;
  c0.u = a.x; c1.u = b.x; r.x = w0 * __bfloat162float(c0.h) + w1 * __bfloat162float(c1.h);
  c0.u = a.y; c1.u = b.y; r.y = w0 * __bfloat162float(c0.h) + w1 * __bfloat162float(c1.h);
  c0.u = a.z; c1.u = b.z; r.z = w0 * __bfloat162float(c0.h) + w1 * __bfloat162float(c1.h);
  c0.u = a.w; c1.u = b.w; r.w = w0 * __bfloat162float(c0.h) + w1 * __bfloat162float(c1.h);
  ((float4*)(outp + (size_t)tok * D_DIM))[i4] = r;
}

// ---------------- launch ----------------
extern "C" void kernel_launch(void* const* d_in, const int* in_sizes, int n_in,
                              void* d_out, int out_size, void* d_ws, size_t ws_size,
                              hipStream_t stream) {
  const float* x = (const float*)d_in[0];
  const float* Wr = (const float*)d_in[1];
  const float* w1 = (const float*)d_in[2];
  const float* w3 = (const float*)d_in[3];
  const float* w2 = (const float*)d_in[4];
  float* outp = (float*)d_out;

  char* ws = (char*)d_ws;
  size_t off = 0;
  auto alloc = [&](size_t bytes) -> char* {
    char* p = ws + off;
    off += (bytes + 255) & ~(size_t)255;
    return p;
  };
  __hip_bfloat16* w13t = (__hip_bfloat16*)alloc((size_t)E_EXP * 2 * H_DIM * D_DIM * 2);
  __hip_bfloat16* w2t = (__hip_bfloat16*)alloc((size_t)E_EXP * D_DIM * H_DIM * 2);
  __hip_bfloat16* Xb = (__hip_bfloat16*)alloc((size_t)T_TOK * D_DIM * 2);
  __hip_bfloat16* Hb = (__hip_bfloat16*)alloc((size_t)CAP_ROWS * H_DIM * 2);
  __hip_bfloat16* Y = (__hip_bfloat16*)alloc((size_t)CAP_ROWS * D_DIM * 2);
  float* slot_w = (float*)alloc(NSLOT * 4);
  int* slot_pos = (int*)alloc(NSLOT * 4);
  int* expert_sel = (int*)alloc(NSLOT * 4);
  int* tok_of_pos = (int*)alloc(CAP_ROWS * 4);
  float* Pbuf = (float*)alloc(2048 * 8 * 4);
  int* cnt = (int*)alloc(256);
  (void)ws_size; (void)in_sizes; (void)n_in; (void)out_size;

  transpose_router<<<dim3(18944), dim3(256), 0, stream>>>(w1, w3, w2, w13t, w2t,
                                                          x, Wr, Pbuf, expert_sel, slot_w, Xb);
  assign_kernel<<<dim3(NSLOT / 256), dim3(256), 0, stream>>>(expert_sel, Pbuf, slot_pos,
                                                             tok_of_pos, cnt,
                                                             outp + (size_t)T_TOK * D_DIM);
  gemm1_kernel<<<dim3((2 * H_DIM / 128) * MT_MAX), dim3(256), 0, stream>>>(Xb, w13t, Hb,
                                                                           tok_of_pos, cnt);
  gemm2_kernel<<<dim3((D_DIM / 128) * MT_MAX), dim3(256), 0, stream>>>(Hb, w2t, Y, cnt);
  combine_kernel<<<dim3(T_TOK), dim3(256), 0, stream>>>(slot_pos, slot_w, Y, outp);
}

// Round 13
// 483.349 us; speedup vs baseline: 1.2269x; 1.0584x over previous
//
#include <hip/hip_runtime.h>
#include <hip/hip_bf16.h>
#include <stdint.h>

// MoE top-2 (T=8192, D=1024, H=2816, E=8) — sparse grouped-GEMM implementation.
// R13: R12 + m-group super-tiling (G=4, n-fastest within group) inside XCD
// chunks for both GEMMs — targets gemm1's 702MB A-side re-fetch. All else
// byte-identical to R12.

#define T_TOK 8192
#define D_DIM 1024
#define H_DIM 2816
#define E_EXP 8
#define NSLOT 16384       // T * 2
#define CAP_ROWS 18432
#define MT_MAX 136        // 128-row tiles

typedef __attribute__((ext_vector_type(8))) short short8;
typedef __attribute__((ext_vector_type(4))) float f32x4;

#define GLD16(gsrc, ldst) __builtin_amdgcn_global_load_lds( \
    (const __attribute__((address_space(1))) void*)(gsrc),  \
    (__attribute__((address_space(3))) void*)(ldst), 16, 0, 0)

// ---------------- merged: weight transposes + router (+Xb bf16 write) ----------------
__global__ __launch_bounds__(256) void transpose_router(const float* __restrict__ w1,
                                                        const float* __restrict__ w3,
                                                        const float* __restrict__ w2,
                                                        __hip_bfloat16* __restrict__ w13t,
                                                        __hip_bfloat16* __restrict__ w2t,
                                                        const float* __restrict__ x,
                                                        const float* __restrict__ Wr,
                                                        float* __restrict__ Pbuf,
                                                        int* __restrict__ expert_sel,
                                                        float* __restrict__ slot_w,
                                                        __hip_bfloat16* __restrict__ Xb) {
  __shared__ float tile[64][65];
  __shared__ float sP[4][8];
  int bid = blockIdx.x, tid = threadIdx.x;
  int lc = (tid & 15) * 4;
  int lr = tid >> 4;
  if (bid < 11264) {
    int z = bid / 704, rem = bid % 704;
    int bx = rem % 44, by = rem / 44;
    int e = z >> 1, w3f = z & 1;
    const float* in = w3f ? w3 : w1;
    int h0 = bx * 64, d0 = by * 64;
    const float* src = in + ((size_t)e * D_DIM + d0) * H_DIM + h0;
#pragma unroll
    for (int i = 0; i < 4; i++) {
      float4 v = *(const float4*)(src + (size_t)(lr + i * 16) * H_DIM + lc);
      tile[lr + i * 16][lc + 0] = v.x;
      tile[lr + i * 16][lc + 1] = v.y;
      tile[lr + i * 16][lc + 2] = v.z;
      tile[lr + i * 16][lc + 3] = v.w;
    }
    __syncthreads();
    __hip_bfloat16* dstE = w13t + (size_t)e * (2 * H_DIM) * D_DIM;
    int rB = (tid & 7) * 8;  // d offset within tile
#pragma unroll
    for (int i = 0; i < 2; i++) {
      int hh = (tid >> 3) + i * 32;
      int habs = h0 + hh;
      int rw = 2 * (habs & ~15) + (habs & 15) + (w3f ? 16 : 0);
      __align__(16) __hip_bfloat16 o[8];
#pragma unroll
      for (int k = 0; k < 8; k++) o[k] = __float2bfloat16(tile[rB + k][hh]);
      *(short8*)(dstE + (size_t)rw * D_DIM + d0 + rB) = *(const short8*)o;
    }
  } else if (bid < 16896) {
    int b2 = bid - 11264;
    int e = b2 / 704, rem = b2 % 704;
    int bx = rem % 16, by = rem / 16;
    int c0 = bx * 64, r0 = by * 64;
    const float* src = w2 + ((size_t)e * H_DIM + r0) * D_DIM + c0;
#pragma unroll
    for (int i = 0; i < 4; i++) {
      float4 v = *(const float4*)(src + (size_t)(lr + i * 16) * D_DIM + lc);
      tile[lr + i * 16][lc + 0] = v.x;
      tile[lr + i * 16][lc + 1] = v.y;
      tile[lr + i * 16][lc + 2] = v.z;
      tile[lr + i * 16][lc + 3] = v.w;
    }
    __syncthreads();
    __hip_bfloat16* dst = w2t + ((size_t)e * D_DIM + c0) * H_DIM + r0;
    int rB = (tid & 7) * 8;
#pragma unroll
    for (int i = 0; i < 2; i++) {
      int c = (tid >> 3) + i * 32;
      __align__(16) __hip_bfloat16 o[8];
#pragma unroll
      for (int k = 0; k < 8; k++) o[k] = __float2bfloat16(tile[rB + k][c]);
      *(short8*)(dst + (size_t)c * H_DIM + rB) = *(const short8*)o;
    }
  } else {
    int rb = bid - 16896;
    int wave = tid >> 6, lane = tid & 63;
    int tok = rb * 4 + wave;
    const float* xr = x + (size_t)tok * D_DIM;
    float acc[8];
#pragma unroll
    for (int e = 0; e < 8; e++) acc[e] = 0.f;
    for (int d = lane; d < D_DIM; d += 64) {
      float xv = xr[d];
      const float4* w4 = (const float4*)(Wr + d * 8);
      float4 wa = w4[0], wb = w4[1];
      acc[0] += xv * wa.x; acc[1] += xv * wa.y; acc[2] += xv * wa.z; acc[3] += xv * wa.w;
      acc[4] += xv * wb.x; acc[5] += xv * wb.y; acc[6] += xv * wb.z; acc[7] += xv * wb.w;
    }
    // x row -> bf16 Xb (for gemm1 indirect A staging)
    const float4* xr4 = (const float4*)xr;
    __hip_bfloat16* xbr = Xb + (size_t)tok * D_DIM;
#pragma unroll
    for (int p = 0; p < 4; p++) {
      float4 v = xr4[p * 64 + lane];
      union { ushort4 u4; __hip_bfloat16 h[4]; } cv;
      cv.h[0] = __float2bfloat16(v.x);
      cv.h[1] = __float2bfloat16(v.y);
      cv.h[2] = __float2bfloat16(v.z);
      cv.h[3] = __float2bfloat16(v.w);
      *(ushort4*)(xbr + (p * 64 + lane) * 4) = cv.u4;
    }
#pragma unroll
    for (int e = 0; e < 8; e++) {
#pragma unroll
      for (int off = 32; off >= 1; off >>= 1) acc[e] += __shfl_xor(acc[e], off);
    }
    float mx = acc[0];
#pragma unroll
    for (int e = 1; e < 8; e++) mx = fmaxf(mx, acc[e]);
    float p[8], s = 0.f;
#pragma unroll
    for (int e = 0; e < 8; e++) { p[e] = expf(acc[e] - mx); s += p[e]; }
    float inv = 1.f / s;
#pragma unroll
    for (int e = 0; e < 8; e++) p[e] *= inv;
    int i0 = 0;
#pragma unroll
    for (int e = 1; e < 8; e++) if (p[e] > p[i0]) i0 = e;
    int i1 = (i0 == 0) ? 1 : 0;
#pragma unroll
    for (int e = 0; e < 8; e++) if (e != i0 && p[e] > p[i1]) i1 = e;
    float wsum = p[i0] + p[i1];
    if (lane == 0) {
      expert_sel[tok * 2] = i0;
      expert_sel[tok * 2 + 1] = i1;
      slot_w[tok * 2] = p[i0] / wsum;
      slot_w[tok * 2 + 1] = p[i1] / wsum;
#pragma unroll
      for (int e = 0; e < 8; e++) sP[wave][e] = p[e];
    }
    __syncthreads();
    if (tid < 8)
      Pbuf[tid * 2048 + rb] = sP[0][tid] + sP[1][tid] + sP[2][tid] + sP[3][tid];
  }
}

// ---------------- assign: self-sufficient (full+prefix histograms, no atomics) ----------------
__global__ __launch_bounds__(256) void assign_kernel(const int* __restrict__ expert_sel,
                                                     const float* __restrict__ Pbuf,
                                                     int* __restrict__ slot_pos,
                                                     int* __restrict__ tok_of_pos,
                                                     int* __restrict__ cnt_out,
                                                     float* __restrict__ aux_out) {
  __shared__ unsigned long long sF[2][4], sQ[2][4];
  __shared__ int wcnt[4][8];
  __shared__ int woff[4][8];
  __shared__ float red[8][33];
  int b = blockIdx.x, tid = threadIdx.x, wave = tid >> 6, lane = tid & 63;
  int myslot = b * 256 + tid;
  int mye = expert_sel[myslot];

  unsigned long long fA = 0, fB = 0, qA = 0, qB = 0;
  int lim = b * 256;
  for (int i = tid; i < NSLOT; i += 256) {
    int e = expert_sel[i];
    if (e < 4) {
      unsigned long long inc = 1ull << (e * 16);
      fA += inc; if (i < lim) qA += inc;
    } else {
      unsigned long long inc = 1ull << ((e - 4) * 16);
      fB += inc; if (i < lim) qB += inc;
    }
  }
#pragma unroll
  for (int off = 32; off >= 1; off >>= 1) {
    fA += __shfl_xor(fA, off); fB += __shfl_xor(fB, off);
    qA += __shfl_xor(qA, off); qB += __shfl_xor(qB, off);
  }
  if (lane == 0) { sF[0][wave] = fA; sF[1][wave] = fB; sQ[0][wave] = qA; sQ[1][wave] = qB; }
  int rank = 0;
#pragma unroll
  for (int ee = 0; ee < 8; ee++) {
    unsigned long long msk = __ballot(mye == ee);
    if (lane == 0) wcnt[wave][ee] = __popcll(msk);
    if (mye == ee) rank = __popcll(msk & ((1ull << lane) - 1ull));
  }
  __syncthreads();
  unsigned long long FA = sF[0][0] + sF[0][1] + sF[0][2] + sF[0][3];
  unsigned long long FB = sF[1][0] + sF[1][1] + sF[1][2] + sF[1][3];
  unsigned long long QA = sQ[0][0] + sQ[0][1] + sQ[0][2] + sQ[0][3];
  unsigned long long QB = sQ[1][0] + sQ[1][1] + sQ[1][2] + sQ[1][3];
  int cnt[8], pre[8];
#pragma unroll
  for (int e2 = 0; e2 < 4; e2++) {
    cnt[e2] = (int)((FA >> (e2 * 16)) & 0xFFFF);
    pre[e2] = (int)((QA >> (e2 * 16)) & 0xFFFF);
    cnt[4 + e2] = (int)((FB >> (e2 * 16)) & 0xFFFF);
    pre[4 + e2] = (int)((QB >> (e2 * 16)) & 0xFFFF);
  }
  if (tid < 8) {
    int c0 = wcnt[0][tid], c1 = wcnt[1][tid], c2 = wcnt[2][tid];
    woff[0][tid] = 0; woff[1][tid] = c0; woff[2][tid] = c0 + c1; woff[3][tid] = c0 + c1 + c2;
    if (b == 0) cnt_out[tid] = cnt[tid];
  }
  __syncthreads();
  int pb = 0;
#pragma unroll
  for (int e2 = 0; e2 < 8; e2++)
    if (e2 < mye) pb += ((cnt[e2] + 127) >> 7) << 7;
  int pos = pb + pre[mye] + woff[wave][mye] + rank;
  slot_pos[myslot] = pos;
  tok_of_pos[pos] = myslot >> 1;

  if (b == 0) {
    int ee = tid >> 5, j = tid & 31;
    float s = 0.f;
    for (int c = j; c < 2048; c += 32) s += Pbuf[ee * 2048 + c];
    red[ee][j] = s;
    __syncthreads();
    if (tid == 0) {
      float aux = 0.f;
      for (int e2 = 0; e2 < 8; e2++) {
        float ss = 0.f;
        for (int k = 0; k < 32; k++) ss += red[e2][k];
        aux += ((float)cnt[e2] / 16384.f) * (ss / 8192.f);
      }
      *aux_out = 8.f * aux;
    }
  }
}

// ---------------- GEMM helpers (BK=64) ----------------
__device__ __forceinline__ short8 frag_read64(const char* tile, int row, int gk) {
  int byte = (row << 7) | ((gk ^ (row & 7)) << 4);
  return *(const short8*)(tile + byte);
}

template <int NITER, int BLK>
__device__ __forceinline__ void stage_rowsT(const __hip_bfloat16* gbase, int ld, char* tile,
                                            int tid) {
#pragma unroll
  for (int i = 0; i < NITER; i++) {
    int L = i * (BLK * 16) + tid * 16;
    int row = L >> 7;
    int g = (L >> 4) & 7;
    int gs = g ^ (row & 7);  // pre-swizzled global source, linear LDS dest
    const char* src = (const char*)(gbase + (size_t)row * ld) + gs * 16;
    GLD16(src, tile + i * (BLK * 16) + (tid >> 6) * 1024);
  }
}

// XCD-chunked + m-group super-tiling: chunk = bid&7 (XCD), within-chunk index
// walks groups of G=4 m-tiles with n fastest inside the group. Requires
// nwg % 8 == 0, nwg % (4*NN) == 0, mmax % 4 == 0.
template <int NN>
__device__ __forceinline__ void tile_from_bid_grp(int bid, int nwg, int* m, int* n) {
  int cpx = nwg >> 3;
  int u = (bid & 7) * cpx + (bid >> 3);
  int mg = u / (4 * NN);
  int r = u % (4 * NN);
  *m = mg * 4 + (r & 3);
  *n = r >> 2;
}

// expert of tile m (tiles are 128-row aligned; row0 = m*128); -1 if beyond total
__device__ __forceinline__ int expert_of_tile(const int* __restrict__ cnt, int m) {
  int acc = 0, e = -1;
#pragma unroll
  for (int ee = 0; ee < 8; ee++) {
    int t = (cnt[ee] + 127) >> 7;
    if (e < 0 && m < acc + t) e = ee;
    acc += t;
  }
  return e;
}

// ---------------- GEMM1: Hb = silu/fuse( Xb[tok] @ w13t^T ), 128x(128 interleaved) ----------------
__global__ __launch_bounds__(256, 2) void gemm1_kernel(const __hip_bfloat16* __restrict__ Xb,
                                                       const __hip_bfloat16* __restrict__ w13t,
                                                       __hip_bfloat16* __restrict__ Hb,
                                                       const int* __restrict__ tok_of_pos,
                                                       const int* __restrict__ cnt) {
  int m, nIdx;
  tile_from_bid_grp<44>(blockIdx.x, (2 * H_DIM / 128) * MT_MAX, &m, &nIdx);
  int e = expert_of_tile(cnt, m);
  if (e < 0) return;
  int row0 = m * 128;
  int n0 = nIdx * 128;  // interleaved-row offset (= 64 h-cols)
  __shared__ __align__(16) char ldsA[16384];
  __shared__ __align__(16) char ldsB[16384];
  int tid = threadIdx.x, wave = tid >> 6, lane = tid & 63;
  int wr = wave >> 1, wc = wave & 1;
  const __hip_bfloat16* Bb = w13t + ((size_t)e * (2 * H_DIM) + n0) * D_DIM;

  const char* srcA[4];
#pragma unroll
  for (int i = 0; i < 4; i++) {
    int row = i * 32 + (tid >> 3);
    int gs = (tid & 7) ^ (row & 7);
    int tk = tok_of_pos[row0 + row] & (T_TOK - 1);  // mask keeps pad rows in-bounds
    srcA[i] = (const char*)(Xb + (size_t)tk * D_DIM) + gs * 16;
  }

  f32x4 acc[4][4];
#pragma unroll
  for (int i = 0; i < 4; i++)
#pragma unroll
    for (int j = 0; j < 4; j++) acc[i][j] = 0.f;

  int rsel = lane & 15, kg = lane >> 4;
  for (int k0 = 0; k0 < D_DIM; k0 += 64) {
#pragma unroll
    for (int i = 0; i < 4; i++)
      GLD16(srcA[i] + (size_t)k0 * 2, ldsA + i * 4096 + wave * 1024);
    stage_rowsT<4, 256>(Bb + k0, D_DIM, ldsB, tid);
    asm volatile("s_waitcnt vmcnt(0)" ::: "memory");
    __syncthreads();
#pragma unroll
    for (int kk = 0; kk < 2; kk++) {
      int gk = kk * 4 + kg;
      short8 a[4], b[4];
#pragma unroll
      for (int f = 0; f < 4; f++) a[f] = frag_read64(ldsA, wr * 64 + f * 16 + rsel, gk);
#pragma unroll
      for (int f = 0; f < 4; f++) b[f] = frag_read64(ldsB, wc * 64 + f * 16 + rsel, gk);
#pragma unroll
      for (int fm = 0; fm < 4; fm++)
#pragma unroll
        for (int fn = 0; fn < 4; fn++)
          acc[fm][fn] = __builtin_amdgcn_mfma_f32_16x16x32_bf16(a[fm], b[fn], acc[fm][fn], 0, 0, 0);
    }
    __syncthreads();
  }
  int rq = lane >> 4;
#pragma unroll
  for (int fm = 0; fm < 4; fm++)
#pragma unroll
    for (int fnp = 0; fnp < 2; fnp++)
#pragma unroll
      for (int j = 0; j < 4; j++) {
        float v1 = acc[fm][2 * fnp][j], v3 = acc[fm][2 * fnp + 1][j];
        float h = (v1 / (1.f + expf(-v1))) * v3;  // silu(v1)*v3
        int r = row0 + wr * 64 + fm * 16 + rq * 4 + j;
        int c = (n0 >> 1) + wc * 32 + fnp * 16 + rsel;
        Hb[(size_t)r * H_DIM + c] = __float2bfloat16(h);
      }
}

// ---------------- GEMM2: Y = Hb @ w2t^T (bf16 out), 128x128 tile ----------------
__global__ __launch_bounds__(256, 2) void gemm2_kernel(const __hip_bfloat16* __restrict__ Hb,
                                                       const __hip_bfloat16* __restrict__ w2t,
                                                       __hip_bfloat16* __restrict__ Y,
                                                       const int* __restrict__ cnt) {
  int m, nIdx;
  tile_from_bid_grp<8>(blockIdx.x, (D_DIM / 128) * MT_MAX, &m, &nIdx);
  int e = expert_of_tile(cnt, m);
  if (e < 0) return;
  int row0 = m * 128;
  int n0 = nIdx * 128;
  __shared__ __align__(16) char ldsA[16384];
  __shared__ __align__(16) char ldsB[16384];
  int tid = threadIdx.x, wave = tid >> 6, lane = tid & 63;
  int wr = wave >> 1, wc = wave & 1;
  const __hip_bfloat16* Ab = Hb + (size_t)row0 * H_DIM;
  const __hip_bfloat16* Bb = w2t + ((size_t)e * D_DIM + n0) * H_DIM;

  f32x4 acc[4][4];
#pragma unroll
  for (int i = 0; i < 4; i++)
#pragma unroll
    for (int j = 0; j < 4; j++) acc[i][j] = 0.f;

  int rsel = lane & 15, kg = lane >> 4;
  for (int k0 = 0; k0 < H_DIM; k0 += 64) {
    stage_rowsT<4, 256>(Ab + k0, H_DIM, ldsA, tid);
    stage_rowsT<4, 256>(Bb + k0, H_DIM, ldsB, tid);
    asm volatile("s_waitcnt vmcnt(0)" ::: "memory");
    __syncthreads();
#pragma unroll
    for (int kk = 0; kk < 2; kk++) {
      int gk = kk * 4 + kg;
      short8 a[4], b[4];
#pragma unroll
      for (int f = 0; f < 4; f++) a[f] = frag_read64(ldsA, wr * 64 + f * 16 + rsel, gk);
#pragma unroll
      for (int f = 0; f < 4; f++) b[f] = frag_read64(ldsB, wc * 64 + f * 16 + rsel, gk);
#pragma unroll
      for (int fm = 0; fm < 4; fm++)
#pragma unroll
        for (int fn = 0; fn < 4; fn++)
          acc[fm][fn] = __builtin_amdgcn_mfma_f32_16x16x32_bf16(a[fm], b[fn], acc[fm][fn], 0, 0, 0);
    }
    __syncthreads();
  }
  int rq = lane >> 4;
#pragma unroll
  for (int fm = 0; fm < 4; fm++)
#pragma unroll
    for (int fn = 0; fn < 4; fn++)
#pragma unroll
      for (int j = 0; j < 4; j++) {
        int r = row0 + wr * 64 + fm * 16 + rq * 4 + j;
        int c = n0 + wc * 64 + fn * 16 + rsel;
        Y[(size_t)r * D_DIM + c] = __float2bfloat16(acc[fm][fn][j]);
      }
}

// ---------------- combine: out[t] = w0*Y[p0] + w1*Y[p1] (bf16 Y) ----------------
__global__ __launch_bounds__(256) void combine_kernel(const int* __restrict__ slot_pos,
                                                      const float* __restrict__ slot_w,
                                                      const __hip_bfloat16* __restrict__ Y,
                                                      float* __restrict__ outp) {
  int tok = blockIdx.x;
  int p0 = slot_pos[tok * 2], p1 = slot_pos[tok * 2 + 1];
  float w0 = slot_w[tok * 2], w1 = slot_w[tok * 2 + 1];
  int i4 = threadIdx.x;  // 256 threads x 4 elems
  ushort4 a = *(const ushort4*)(Y + (size_t)p0 * D_DIM + i4 * 4);
  ushort4 b = *(const ushort4*)(Y + (size_t)p1 * D_DIM + i4 * 4);
  union { ushort u; __hip_bfloat16 h; } c0, c1;
  float4 r;
  c0.u = a.x; c1.u = b.x; r.x = w0 * __bfloat162float(c0.h) + w1 * __bfloat162float(c1.h);
  c0.u = a.y; c1.u = b.y; r.y = w0 * __bfloat162float(c0.h) + w1 * __bfloat162float(c1.h);
  c0.u = a.z; c1.u = b.z; r.z = w0 * __bfloat162float(c0.h) + w1 * __bfloat162float(c1.h);
  c0.u = a.w; c1.u = b.w; r.w = w0 * __bfloat162float(c0.h) + w1 * __bfloat162float(c1.h);
  ((float4*)(outp + (size_t)tok * D_DIM))[i4] = r;
}

// ---------------- launch ----------------
extern "C" void kernel_launch(void* const* d_in, const int* in_sizes, int n_in,
                              void* d_out, int out_size, void* d_ws, size_t ws_size,
                              hipStream_t stream) {
  const float* x = (const float*)d_in[0];
  const float* Wr = (const float*)d_in[1];
  const float* w1 = (const float*)d_in[2];
  const float* w3 = (const float*)d_in[3];
  const float* w2 = (const float*)d_in[4];
  float* outp = (float*)d_out;

  char* ws = (char*)d_ws;
  size_t off = 0;
  auto alloc = [&](size_t bytes) -> char* {
    char* p = ws + off;
    off += (bytes + 255) & ~(size_t)255;
    return p;
  };
  __hip_bfloat16* w13t = (__hip_bfloat16*)alloc((size_t)E_EXP * 2 * H_DIM * D_DIM * 2);
  __hip_bfloat16* w2t = (__hip_bfloat16*)alloc((size_t)E_EXP * D_DIM * H_DIM * 2);
  __hip_bfloat16* Xb = (__hip_bfloat16*)alloc((size_t)T_TOK * D_DIM * 2);
  __hip_bfloat16* Hb = (__hip_bfloat16*)alloc((size_t)CAP_ROWS * H_DIM * 2);
  __hip_bfloat16* Y = (__hip_bfloat16*)alloc((size_t)CAP_ROWS * D_DIM * 2);
  float* slot_w = (float*)alloc(NSLOT * 4);
  int* slot_pos = (int*)alloc(NSLOT * 4);
  int* expert_sel = (int*)alloc(NSLOT * 4);
  int* tok_of_pos = (int*)alloc(CAP_ROWS * 4);
  float* Pbuf = (float*)alloc(2048 * 8 * 4);
  int* cnt = (int*)alloc(256);
  (void)ws_size; (void)in_sizes; (void)n_in; (void)out_size;

  transpose_router<<<dim3(18944), dim3(256), 0, stream>>>(w1, w3, w2, w13t, w2t,
                                                          x, Wr, Pbuf, expert_sel, slot_w, Xb);
  assign_kernel<<<dim3(NSLOT / 256), dim3(256), 0, stream>>>(expert_sel, Pbuf, slot_pos,
                                                             tok_of_pos, cnt,
                                                             outp + (size_t)T_TOK * D_DIM);
  gemm1_kernel<<<dim3((2 * H_DIM / 128) * MT_MAX), dim3(256), 0, stream>>>(Xb, w13t, Hb,
                                                                           tok_of_pos, cnt);
  gemm2_kernel<<<dim3((D_DIM / 128) * MT_MAX), dim3(256), 0, stream>>>(Hb, w2t, Y, cnt);
  combine_kernel<<<dim3(T_TOK), dim3(256), 0, stream>>>(slot_pos, slot_w, Y, outp);
}

// Round 14
// 470.574 us; speedup vs baseline: 1.2602x; 1.0271x over previous
//
#include <hip/hip_runtime.h>
#include <hip/hip_bf16.h>
#include <stdint.h>

// MoE top-2 (T=8192, D=1024, H=2816, E=8) — sparse grouped-GEMM implementation.
// R14: R13 + split-K=2 gemm2 (2176 blocks, halves per-tile latency -> tail
// quantization cost; bf16 half-sums folded in combine). All else identical.

#define T_TOK 8192
#define D_DIM 1024
#define H_DIM 2816
#define E_EXP 8
#define NSLOT 16384       // T * 2
#define CAP_ROWS 18432
#define MT_MAX 136        // 128-row tiles

typedef __attribute__((ext_vector_type(8))) short short8;
typedef __attribute__((ext_vector_type(4))) float f32x4;

#define GLD16(gsrc, ldst) __builtin_amdgcn_global_load_lds( \
    (const __attribute__((address_space(1))) void*)(gsrc),  \
    (__attribute__((address_space(3))) void*)(ldst), 16, 0, 0)

// ---------------- merged: weight transposes + router (+Xb bf16 write) ----------------
__global__ __launch_bounds__(256) void transpose_router(const float* __restrict__ w1,
                                                        const float* __restrict__ w3,
                                                        const float* __restrict__ w2,
                                                        __hip_bfloat16* __restrict__ w13t,
                                                        __hip_bfloat16* __restrict__ w2t,
                                                        const float* __restrict__ x,
                                                        const float* __restrict__ Wr,
                                                        float* __restrict__ Pbuf,
                                                        int* __restrict__ expert_sel,
                                                        float* __restrict__ slot_w,
                                                        __hip_bfloat16* __restrict__ Xb) {
  __shared__ float tile[64][65];
  __shared__ float sP[4][8];
  int bid = blockIdx.x, tid = threadIdx.x;
  int lc = (tid & 15) * 4;
  int lr = tid >> 4;
  if (bid < 11264) {
    int z = bid / 704, rem = bid % 704;
    int bx = rem % 44, by = rem / 44;
    int e = z >> 1, w3f = z & 1;
    const float* in = w3f ? w3 : w1;
    int h0 = bx * 64, d0 = by * 64;
    const float* src = in + ((size_t)e * D_DIM + d0) * H_DIM + h0;
#pragma unroll
    for (int i = 0; i < 4; i++) {
      float4 v = *(const float4*)(src + (size_t)(lr + i * 16) * H_DIM + lc);
      tile[lr + i * 16][lc + 0] = v.x;
      tile[lr + i * 16][lc + 1] = v.y;
      tile[lr + i * 16][lc + 2] = v.z;
      tile[lr + i * 16][lc + 3] = v.w;
    }
    __syncthreads();
    __hip_bfloat16* dstE = w13t + (size_t)e * (2 * H_DIM) * D_DIM;
    int rB = (tid & 7) * 8;  // d offset within tile
#pragma unroll
    for (int i = 0; i < 2; i++) {
      int hh = (tid >> 3) + i * 32;
      int habs = h0 + hh;
      int rw = 2 * (habs & ~15) + (habs & 15) + (w3f ? 16 : 0);
      __align__(16) __hip_bfloat16 o[8];
#pragma unroll
      for (int k = 0; k < 8; k++) o[k] = __float2bfloat16(tile[rB + k][hh]);
      *(short8*)(dstE + (size_t)rw * D_DIM + d0 + rB) = *(const short8*)o;
    }
  } else if (bid < 16896) {
    int b2 = bid - 11264;
    int e = b2 / 704, rem = b2 % 704;
    int bx = rem % 16, by = rem / 16;
    int c0 = bx * 64, r0 = by * 64;
    const float* src = w2 + ((size_t)e * H_DIM + r0) * D_DIM + c0;
#pragma unroll
    for (int i = 0; i < 4; i++) {
      float4 v = *(const float4*)(src + (size_t)(lr + i * 16) * D_DIM + lc);
      tile[lr + i * 16][lc + 0] = v.x;
      tile[lr + i * 16][lc + 1] = v.y;
      tile[lr + i * 16][lc + 2] = v.z;
      tile[lr + i * 16][lc + 3] = v.w;
    }
    __syncthreads();
    __hip_bfloat16* dst = w2t + ((size_t)e * D_DIM + c0) * H_DIM + r0;
    int rB = (tid & 7) * 8;
#pragma unroll
    for (int i = 0; i < 2; i++) {
      int c = (tid >> 3) + i * 32;
      __align__(16) __hip_bfloat16 o[8];
#pragma unroll
      for (int k = 0; k < 8; k++) o[k] = __float2bfloat16(tile[rB + k][c]);
      *(short8*)(dst + (size_t)c * H_DIM + rB) = *(const short8*)o;
    }
  } else {
    int rb = bid - 16896;
    int wave = tid >> 6, lane = tid & 63;
    int tok = rb * 4 + wave;
    const float* xr = x + (size_t)tok * D_DIM;
    float acc[8];
#pragma unroll
    for (int e = 0; e < 8; e++) acc[e] = 0.f;
    for (int d = lane; d < D_DIM; d += 64) {
      float xv = xr[d];
      const float4* w4 = (const float4*)(Wr + d * 8);
      float4 wa = w4[0], wb = w4[1];
      acc[0] += xv * wa.x; acc[1] += xv * wa.y; acc[2] += xv * wa.z; acc[3] += xv * wa.w;
      acc[4] += xv * wb.x; acc[5] += xv * wb.y; acc[6] += xv * wb.z; acc[7] += xv * wb.w;
    }
    // x row -> bf16 Xb (for gemm1 indirect A staging)
    const float4* xr4 = (const float4*)xr;
    __hip_bfloat16* xbr = Xb + (size_t)tok * D_DIM;
#pragma unroll
    for (int p = 0; p < 4; p++) {
      float4 v = xr4[p * 64 + lane];
      union { ushort4 u4; __hip_bfloat16 h[4]; } cv;
      cv.h[0] = __float2bfloat16(v.x);
      cv.h[1] = __float2bfloat16(v.y);
      cv.h[2] = __float2bfloat16(v.z);
      cv.h[3] = __float2bfloat16(v.w);
      *(ushort4*)(xbr + (p * 64 + lane) * 4) = cv.u4;
    }
#pragma unroll
    for (int e = 0; e < 8; e++) {
#pragma unroll
      for (int off = 32; off >= 1; off >>= 1) acc[e] += __shfl_xor(acc[e], off);
    }
    float mx = acc[0];
#pragma unroll
    for (int e = 1; e < 8; e++) mx = fmaxf(mx, acc[e]);
    float p[8], s = 0.f;
#pragma unroll
    for (int e = 0; e < 8; e++) { p[e] = expf(acc[e] - mx); s += p[e]; }
    float inv = 1.f / s;
#pragma unroll
    for (int e = 0; e < 8; e++) p[e] *= inv;
    int i0 = 0;
#pragma unroll
    for (int e = 1; e < 8; e++) if (p[e] > p[i0]) i0 = e;
    int i1 = (i0 == 0) ? 1 : 0;
#pragma unroll
    for (int e = 0; e < 8; e++) if (e != i0 && p[e] > p[i1]) i1 = e;
    float wsum = p[i0] + p[i1];
    if (lane == 0) {
      expert_sel[tok * 2] = i0;
      expert_sel[tok * 2 + 1] = i1;
      slot_w[tok * 2] = p[i0] / wsum;
      slot_w[tok * 2 + 1] = p[i1] / wsum;
#pragma unroll
      for (int e = 0; e < 8; e++) sP[wave][e] = p[e];
    }
    __syncthreads();
    if (tid < 8)
      Pbuf[tid * 2048 + rb] = sP[0][tid] + sP[1][tid] + sP[2][tid] + sP[3][tid];
  }
}

// ---------------- assign: self-sufficient (full+prefix histograms, no atomics) ----------------
__global__ __launch_bounds__(256) void assign_kernel(const int* __restrict__ expert_sel,
                                                     const float* __restrict__ Pbuf,
                                                     int* __restrict__ slot_pos,
                                                     int* __restrict__ tok_of_pos,
                                                     int* __restrict__ cnt_out,
                                                     float* __restrict__ aux_out) {
  __shared__ unsigned long long sF[2][4], sQ[2][4];
  __shared__ int wcnt[4][8];
  __shared__ int woff[4][8];
  __shared__ float red[8][33];
  int b = blockIdx.x, tid = threadIdx.x, wave = tid >> 6, lane = tid & 63;
  int myslot = b * 256 + tid;
  int mye = expert_sel[myslot];

  unsigned long long fA = 0, fB = 0, qA = 0, qB = 0;
  int lim = b * 256;
  for (int i = tid; i < NSLOT; i += 256) {
    int e = expert_sel[i];
    if (e < 4) {
      unsigned long long inc = 1ull << (e * 16);
      fA += inc; if (i < lim) qA += inc;
    } else {
      unsigned long long inc = 1ull << ((e - 4) * 16);
      fB += inc; if (i < lim) qB += inc;
    }
  }
#pragma unroll
  for (int off = 32; off >= 1; off >>= 1) {
    fA += __shfl_xor(fA, off); fB += __shfl_xor(fB, off);
    qA += __shfl_xor(qA, off); qB += __shfl_xor(qB, off);
  }
  if (lane == 0) { sF[0][wave] = fA; sF[1][wave] = fB; sQ[0][wave] = qA; sQ[1][wave] = qB; }
  int rank = 0;
#pragma unroll
  for (int ee = 0; ee < 8; ee++) {
    unsigned long long msk = __ballot(mye == ee);
    if (lane == 0) wcnt[wave][ee] = __popcll(msk);
    if (mye == ee) rank = __popcll(msk & ((1ull << lane) - 1ull));
  }
  __syncthreads();
  unsigned long long FA = sF[0][0] + sF[0][1] + sF[0][2] + sF[0][3];
  unsigned long long FB = sF[1][0] + sF[1][1] + sF[1][2] + sF[1][3];
  unsigned long long QA = sQ[0][0] + sQ[0][1] + sQ[0][2] + sQ[0][3];
  unsigned long long QB = sQ[1][0] + sQ[1][1] + sQ[1][2] + sQ[1][3];
  int cnt[8], pre[8];
#pragma unroll
  for (int e2 = 0; e2 < 4; e2++) {
    cnt[e2] = (int)((FA >> (e2 * 16)) & 0xFFFF);
    pre[e2] = (int)((QA >> (e2 * 16)) & 0xFFFF);
    cnt[4 + e2] = (int)((FB >> (e2 * 16)) & 0xFFFF);
    pre[4 + e2] = (int)((QB >> (e2 * 16)) & 0xFFFF);
  }
  if (tid < 8) {
    int c0 = wcnt[0][tid], c1 = wcnt[1][tid], c2 = wcnt[2][tid];
    woff[0][tid] = 0; woff[1][tid] = c0; woff[2][tid] = c0 + c1; woff[3][tid] = c0 + c1 + c2;
    if (b == 0) cnt_out[tid] = cnt[tid];
  }
  __syncthreads();
  int pb = 0;
#pragma unroll
  for (int e2 = 0; e2 < 8; e2++)
    if (e2 < mye) pb += ((cnt[e2] + 127) >> 7) << 7;
  int pos = pb + pre[mye] + woff[wave][mye] + rank;
  slot_pos[myslot] = pos;
  tok_of_pos[pos] = myslot >> 1;

  if (b == 0) {
    int ee = tid >> 5, j = tid & 31;
    float s = 0.f;
    for (int c = j; c < 2048; c += 32) s += Pbuf[ee * 2048 + c];
    red[ee][j] = s;
    __syncthreads();
    if (tid == 0) {
      float aux = 0.f;
      for (int e2 = 0; e2 < 8; e2++) {
        float ss = 0.f;
        for (int k = 0; k < 32; k++) ss += red[e2][k];
        aux += ((float)cnt[e2] / 16384.f) * (ss / 8192.f);
      }
      *aux_out = 8.f * aux;
    }
  }
}

// ---------------- GEMM helpers (BK=64) ----------------
__device__ __forceinline__ short8 frag_read64(const char* tile, int row, int gk) {
  int byte = (row << 7) | ((gk ^ (row & 7)) << 4);
  return *(const short8*)(tile + byte);
}

template <int NITER, int BLK>
__device__ __forceinline__ void stage_rowsT(const __hip_bfloat16* gbase, int ld, char* tile,
                                            int tid) {
#pragma unroll
  for (int i = 0; i < NITER; i++) {
    int L = i * (BLK * 16) + tid * 16;
    int row = L >> 7;
    int g = (L >> 4) & 7;
    int gs = g ^ (row & 7);  // pre-swizzled global source, linear LDS dest
    const char* src = (const char*)(gbase + (size_t)row * ld) + gs * 16;
    GLD16(src, tile + i * (BLK * 16) + (tid >> 6) * 1024);
  }
}

// XCD-chunked + m-group super-tiling (G=4 m-tiles, n fastest in group)
template <int NN>
__device__ __forceinline__ void tile_from_bid_grp(int bid, int nwg, int* m, int* n) {
  int cpx = nwg >> 3;
  int u = (bid & 7) * cpx + (bid >> 3);
  int mg = u / (4 * NN);
  int r = u % (4 * NN);
  *m = mg * 4 + (r & 3);
  *n = r >> 2;
}

// expert of tile m (tiles are 128-row aligned; row0 = m*128); -1 if beyond total
__device__ __forceinline__ int expert_of_tile(const int* __restrict__ cnt, int m) {
  int acc = 0, e = -1;
#pragma unroll
  for (int ee = 0; ee < 8; ee++) {
    int t = (cnt[ee] + 127) >> 7;
    if (e < 0 && m < acc + t) e = ee;
    acc += t;
  }
  return e;
}

// ---------------- GEMM1: Hb = silu/fuse( Xb[tok] @ w13t^T ), 128x(128 interleaved) ----------------
__global__ __launch_bounds__(256, 2) void gemm1_kernel(const __hip_bfloat16* __restrict__ Xb,
                                                       const __hip_bfloat16* __restrict__ w13t,
                                                       __hip_bfloat16* __restrict__ Hb,
                                                       const int* __restrict__ tok_of_pos,
                                                       const int* __restrict__ cnt) {
  int m, nIdx;
  tile_from_bid_grp<44>(blockIdx.x, (2 * H_DIM / 128) * MT_MAX, &m, &nIdx);
  int e = expert_of_tile(cnt, m);
  if (e < 0) return;
  int row0 = m * 128;
  int n0 = nIdx * 128;  // interleaved-row offset (= 64 h-cols)
  __shared__ __align__(16) char ldsA[16384];
  __shared__ __align__(16) char ldsB[16384];
  int tid = threadIdx.x, wave = tid >> 6, lane = tid & 63;
  int wr = wave >> 1, wc = wave & 1;
  const __hip_bfloat16* Bb = w13t + ((size_t)e * (2 * H_DIM) + n0) * D_DIM;

  const char* srcA[4];
#pragma unroll
  for (int i = 0; i < 4; i++) {
    int row = i * 32 + (tid >> 3);
    int gs = (tid & 7) ^ (row & 7);
    int tk = tok_of_pos[row0 + row] & (T_TOK - 1);  // mask keeps pad rows in-bounds
    srcA[i] = (const char*)(Xb + (size_t)tk * D_DIM) + gs * 16;
  }

  f32x4 acc[4][4];
#pragma unroll
  for (int i = 0; i < 4; i++)
#pragma unroll
    for (int j = 0; j < 4; j++) acc[i][j] = 0.f;

  int rsel = lane & 15, kg = lane >> 4;
  for (int k0 = 0; k0 < D_DIM; k0 += 64) {
#pragma unroll
    for (int i = 0; i < 4; i++)
      GLD16(srcA[i] + (size_t)k0 * 2, ldsA + i * 4096 + wave * 1024);
    stage_rowsT<4, 256>(Bb + k0, D_DIM, ldsB, tid);
    asm volatile("s_waitcnt vmcnt(0)" ::: "memory");
    __syncthreads();
#pragma unroll
    for (int kk = 0; kk < 2; kk++) {
      int gk = kk * 4 + kg;
      short8 a[4], b[4];
#pragma unroll
      for (int f = 0; f < 4; f++) a[f] = frag_read64(ldsA, wr * 64 + f * 16 + rsel, gk);
#pragma unroll
      for (int f = 0; f < 4; f++) b[f] = frag_read64(ldsB, wc * 64 + f * 16 + rsel, gk);
#pragma unroll
      for (int fm = 0; fm < 4; fm++)
#pragma unroll
        for (int fn = 0; fn < 4; fn++)
          acc[fm][fn] = __builtin_amdgcn_mfma_f32_16x16x32_bf16(a[fm], b[fn], acc[fm][fn], 0, 0, 0);
    }
    __syncthreads();
  }
  int rq = lane >> 4;
#pragma unroll
  for (int fm = 0; fm < 4; fm++)
#pragma unroll
    for (int fnp = 0; fnp < 2; fnp++)
#pragma unroll
      for (int j = 0; j < 4; j++) {
        float v1 = acc[fm][2 * fnp][j], v3 = acc[fm][2 * fnp + 1][j];
        float h = (v1 / (1.f + expf(-v1))) * v3;  // silu(v1)*v3
        int r = row0 + wr * 64 + fm * 16 + rq * 4 + j;
        int c = (n0 >> 1) + wc * 32 + fnp * 16 + rsel;
        Hb[(size_t)r * H_DIM + c] = __float2bfloat16(h);
      }
}

// ---------------- GEMM2: Y2[kh] = Hb @ w2t^T over K-half (bf16 out), 128x128 ----------------
__global__ __launch_bounds__(256, 2) void gemm2_kernel(const __hip_bfloat16* __restrict__ Hb,
                                                       const __hip_bfloat16* __restrict__ w2t,
                                                       __hip_bfloat16* __restrict__ Y2,
                                                       const int* __restrict__ cnt) {
  int m, np;
  // nwg = 16 * MT_MAX = 2176; n' packs (n, kh): n = n'>>1, kh = n'&1
  tile_from_bid_grp<16>(blockIdx.x, 16 * MT_MAX, &m, &np);
  int e = expert_of_tile(cnt, m);
  if (e < 0) return;
  int nIdx = np >> 1, kh = np & 1;
  int row0 = m * 128;
  int n0 = nIdx * 128;
  __shared__ __align__(16) char ldsA[16384];
  __shared__ __align__(16) char ldsB[16384];
  int tid = threadIdx.x, wave = tid >> 6, lane = tid & 63;
  int wr = wave >> 1, wc = wave & 1;
  const __hip_bfloat16* Ab = Hb + (size_t)row0 * H_DIM;
  const __hip_bfloat16* Bb = w2t + ((size_t)e * D_DIM + n0) * H_DIM;

  f32x4 acc[4][4];
#pragma unroll
  for (int i = 0; i < 4; i++)
#pragma unroll
    for (int j = 0; j < 4; j++) acc[i][j] = 0.f;

  int rsel = lane & 15, kg = lane >> 4;
  int kbeg = kh * (H_DIM / 2), kend = kbeg + (H_DIM / 2);
  for (int k0 = kbeg; k0 < kend; k0 += 64) {
    stage_rowsT<4, 256>(Ab + k0, H_DIM, ldsA, tid);
    stage_rowsT<4, 256>(Bb + k0, H_DIM, ldsB, tid);
    asm volatile("s_waitcnt vmcnt(0)" ::: "memory");
    __syncthreads();
#pragma unroll
    for (int kk = 0; kk < 2; kk++) {
      int gk = kk * 4 + kg;
      short8 a[4], b[4];
#pragma unroll
      for (int f = 0; f < 4; f++) a[f] = frag_read64(ldsA, wr * 64 + f * 16 + rsel, gk);
#pragma unroll
      for (int f = 0; f < 4; f++) b[f] = frag_read64(ldsB, wc * 64 + f * 16 + rsel, gk);
#pragma unroll
      for (int fm = 0; fm < 4; fm++)
#pragma unroll
        for (int fn = 0; fn < 4; fn++)
          acc[fm][fn] = __builtin_amdgcn_mfma_f32_16x16x32_bf16(a[fm], b[fn], acc[fm][fn], 0, 0, 0);
    }
    __syncthreads();
  }
  int rq = lane >> 4;
  __hip_bfloat16* Yh = Y2 + (size_t)kh * CAP_ROWS * D_DIM;
#pragma unroll
  for (int fm = 0; fm < 4; fm++)
#pragma unroll
    for (int fn = 0; fn < 4; fn++)
#pragma unroll
      for (int j = 0; j < 4; j++) {
        int r = row0 + wr * 64 + fm * 16 + rq * 4 + j;
        int c = n0 + wc * 64 + fn * 16 + rsel;
        Yh[(size_t)r * D_DIM + c] = __float2bfloat16(acc[fm][fn][j]);
      }
}

// ---------------- combine: out[t] = w0*(Y0[p0]+Y1[p0]) + w1*(Y0[p1]+Y1[p1]) ----------------
__global__ __launch_bounds__(256) void combine_kernel(const int* __restrict__ slot_pos,
                                                      const float* __restrict__ slot_w,
                                                      const __hip_bfloat16* __restrict__ Y2,
                                                      float* __restrict__ outp) {
  int tok = blockIdx.x;
  int p0 = slot_pos[tok * 2], p1 = slot_pos[tok * 2 + 1];
  float w0 = slot_w[tok * 2], w1 = slot_w[tok * 2 + 1];
  int i4 = threadIdx.x;  // 256 threads x 4 elems
  const __hip_bfloat16* Y0 = Y2;
  const __hip_bfloat16* Y1 = Y2 + (size_t)CAP_ROWS * D_DIM;
  ushort4 a0 = *(const ushort4*)(Y0 + (size_t)p0 * D_DIM + i4 * 4);
  ushort4 a1 = *(const ushort4*)(Y1 + (size_t)p0 * D_DIM + i4 * 4);
  ushort4 b0 = *(const ushort4*)(Y0 + (size_t)p1 * D_DIM + i4 * 4);
  ushort4 b1 = *(const ushort4*)(Y1 + (size_t)p1 * D_DIM + i4 * 4);
  union { ushort u; __hip_bfloat16 h; } c;
  float4 r;
#define CMB(comp) { float fa0, fa1, fb0, fb1; \
    c.u = a0.comp; fa0 = __bfloat162float(c.h); \
    c.u = a1.comp; fa1 = __bfloat162float(c.h); \
    c.u = b0.comp; fb0 = __bfloat162float(c.h); \
    c.u = b1.comp; fb1 = __bfloat162float(c.h); \
    r.comp = w0 * (fa0 + fa1) + w1 * (fb0 + fb1); }
  CMB(x) CMB(y) CMB(z) CMB(w)
#undef CMB
  ((float4*)(outp + (size_t)tok * D_DIM))[i4] = r;
}

// ---------------- launch ----------------
extern "C" void kernel_launch(void* const* d_in, const int* in_sizes, int n_in,
                              void* d_out, int out_size, void* d_ws, size_t ws_size,
                              hipStream_t stream) {
  const float* x = (const float*)d_in[0];
  const float* Wr = (const float*)d_in[1];
  const float* w1 = (const float*)d_in[2];
  const float* w3 = (const float*)d_in[3];
  const float* w2 = (const float*)d_in[4];
  float* outp = (float*)d_out;

  char* ws = (char*)d_ws;
  size_t off = 0;
  auto alloc = [&](size_t bytes) -> char* {
    char* p = ws + off;
    off += (bytes + 255) & ~(size_t)255;
    return p;
  };
  __hip_bfloat16* w13t = (__hip_bfloat16*)alloc((size_t)E_EXP * 2 * H_DIM * D_DIM * 2);
  __hip_bfloat16* w2t = (__hip_bfloat16*)alloc((size_t)E_EXP * D_DIM * H_DIM * 2);
  __hip_bfloat16* Xb = (__hip_bfloat16*)alloc((size_t)T_TOK * D_DIM * 2);
  __hip_bfloat16* Hb = (__hip_bfloat16*)alloc((size_t)CAP_ROWS * H_DIM * 2);
  __hip_bfloat16* Y2 = (__hip_bfloat16*)alloc((size_t)2 * CAP_ROWS * D_DIM * 2);
  float* slot_w = (float*)alloc(NSLOT * 4);
  int* slot_pos = (int*)alloc(NSLOT * 4);
  int* expert_sel = (int*)alloc(NSLOT * 4);
  int* tok_of_pos = (int*)alloc(CAP_ROWS * 4);
  float* Pbuf = (float*)alloc(2048 * 8 * 4);
  int* cnt = (int*)alloc(256);
  (void)ws_size; (void)in_sizes; (void)n_in; (void)out_size;

  transpose_router<<<dim3(18944), dim3(256), 0, stream>>>(w1, w3, w2, w13t, w2t,
                                                          x, Wr, Pbuf, expert_sel, slot_w, Xb);
  assign_kernel<<<dim3(NSLOT / 256), dim3(256), 0, stream>>>(expert_sel, Pbuf, slot_pos,
                                                             tok_of_pos, cnt,
                                                             outp + (size_t)T_TOK * D_DIM);
  gemm1_kernel<<<dim3((2 * H_DIM / 128) * MT_MAX), dim3(256), 0, stream>>>(Xb, w13t, Hb,
                                                                           tok_of_pos, cnt);
  gemm2_kernel<<<dim3(16 * MT_MAX), dim3(256), 0, stream>>>(Hb, w2t, Y2, cnt);
  combine_kernel<<<dim3(T_TOK), dim3(256), 0, stream>>>(slot_pos, slot_w, Y2, outp);
}